// Round 1
// baseline (3827.934 us; speedup 1.0000x reference)
//
#include <hip/hip_runtime.h>

#define NN 20000
#define NE 320000
#define NG 256
// NA=23, NB=7, M0=64, M1=24, M2=16

__global__ __launch_bounds__(256) void k_phase1(
    const float* __restrict__ pos,
    const float* __restrict__ x,
    const float* __restrict__ eag,
    const int* __restrict__ esrc,
    const int* __restrict__ edst,
    const float* __restrict__ W1,
    const float* __restrict__ W2,
    const float* __restrict__ W3,
    float* __restrict__ n0,
    float* __restrict__ n1,
    float* __restrict__ n2)
{
    const int e = blockIdx.x * blockDim.x + threadIdx.x;
    if (e >= NE) return;
    const int s = esrc[e];
    const int d = edst[e];
    const float px = pos[3*s+0] - pos[3*d+0];
    const float py = pos[3*s+1] - pos[3*d+1];
    const float pz = pos[3*s+2] - pos[3*d+2];

    float ea[7];
#pragma unroll
    for (int v = 0; v < 7; ++v) ea[v] = eag[e*7 + v];

    float h1[64], h2[24], h3[16];
#pragma unroll
    for (int w = 0; w < 64; ++w) h1[w] = 0.f;
#pragma unroll
    for (int w = 0; w < 24; ++w) h2[w] = 0.f;
#pragma unroll
    for (int w = 0; w < 16; ++w) h3[w] = 0.f;

    // h_k[w] = sum_{u,v} x[s,u]*ea[v]*Wk[u,v,w]
    for (int u = 0; u < 23; ++u) {
        const float xu = x[s*23 + u];
#pragma unroll
        for (int v = 0; v < 7; ++v) {
            const float p = xu * ea[v];
            const int base = u*7 + v;
            const float4* w1 = (const float4*)(W1 + base*64);
#pragma unroll
            for (int q = 0; q < 16; ++q) {
                const float4 wv = w1[q];
                h1[4*q+0] += p * wv.x;
                h1[4*q+1] += p * wv.y;
                h1[4*q+2] += p * wv.z;
                h1[4*q+3] += p * wv.w;
            }
            const float4* w2 = (const float4*)(W2 + base*24);
#pragma unroll
            for (int q = 0; q < 6; ++q) {
                const float4 wv = w2[q];
                h2[4*q+0] += p * wv.x;
                h2[4*q+1] += p * wv.y;
                h2[4*q+2] += p * wv.z;
                h2[4*q+3] += p * wv.w;
            }
            const float4* w3 = (const float4*)(W3 + base*16);
#pragma unroll
            for (int q = 0; q < 4; ++q) {
                const float4 wv = w3[q];
                h3[4*q+0] += p * wv.x;
                h3[4*q+1] += p * wv.y;
                h3[4*q+2] += p * wv.z;
                h3[4*q+3] += p * wv.w;
            }
        }
    }

    const float r2 = px*px + py*py + pz*pz;
    const float sh1v[3] = {1.7320508f*px, 1.7320508f*py, 1.7320508f*pz};
    const float sh2v[5] = {3.8729833f*px*py,
                           3.8729833f*py*pz,
                           0.5f*2.2360680f*(3.f*pz*pz - r2),
                           3.8729833f*px*pz,
                           0.5f*3.8729833f*(px*px - py*py)};
    const float a1 = 0.07881104f;  // 1/sqrt(23*7)

    float* n0d = n0 + (size_t)d*64;
#pragma unroll
    for (int w = 0; w < 64; ++w) unsafeAtomicAdd(&n0d[w], a1*h1[w]);

    float* n1d = n1 + (size_t)d*72;  // [w][m], m fastest
#pragma unroll
    for (int w = 0; w < 24; ++w) {
        const float t = a1*h2[w];
#pragma unroll
        for (int m = 0; m < 3; ++m) unsafeAtomicAdd(&n1d[w*3+m], t*sh1v[m]);
    }
    float* n2d = n2 + (size_t)d*80;  // [w][m]
#pragma unroll
    for (int w = 0; w < 16; ++w) {
        const float t = a1*h3[w];
#pragma unroll
        for (int m = 0; m < 5; ++m) unsafeAtomicAdd(&n2d[w*5+m], t*sh2v[m]);
    }
}

__global__ __launch_bounds__(256) void k_phase2(
    const float* __restrict__ pos,
    const float* __restrict__ eag,
    const int* __restrict__ esrc,
    const int* __restrict__ edst,
    const float* __restrict__ V1,
    const float* __restrict__ V2,
    const float* __restrict__ V3,
    const float* __restrict__ n0,
    const float* __restrict__ n1,
    const float* __restrict__ n2,
    float* __restrict__ node_out)
{
    const int e = blockIdx.x * blockDim.x + threadIdx.x;
    if (e >= NE) return;
    const int s = esrc[e];
    const int d = edst[e];
    const float px = pos[3*s+0] - pos[3*d+0];
    const float py = pos[3*s+1] - pos[3*d+1];
    const float pz = pos[3*s+2] - pos[3*d+2];

    float ea[7];
#pragma unroll
    for (int v = 0; v < 7; ++v) ea[v] = eag[e*7 + v];

    // term0: g0 = sum_v ea[v] * sum_u n0[s,u]*V1[u,v]
    float r0[7];
#pragma unroll
    for (int v = 0; v < 7; ++v) r0[v] = 0.f;
    const float* n0s = n0 + (size_t)s*64;
    for (int u = 0; u < 64; ++u) {
        const float nu = n0s[u];
        const float* vr = V1 + u*7;
#pragma unroll
        for (int v = 0; v < 7; ++v) r0[v] += nu * vr[v];
    }
    float g0 = 0.f;
#pragma unroll
    for (int v = 0; v < 7; ++v) g0 += ea[v]*r0[v];

    // term1: A[m][v] = sum_u n1[s,u,m]*V2[u,v]
    float A[3][7];
#pragma unroll
    for (int m = 0; m < 3; ++m)
#pragma unroll
        for (int v = 0; v < 7; ++v) A[m][v] = 0.f;
    const float* n1s = n1 + (size_t)s*72;
    for (int u = 0; u < 24; ++u) {
        const float b0 = n1s[u*3+0];
        const float b1 = n1s[u*3+1];
        const float b2 = n1s[u*3+2];
        const float* vr = V2 + u*7;
#pragma unroll
        for (int v = 0; v < 7; ++v) {
            const float vv = vr[v];
            A[0][v] += b0*vv;
            A[1][v] += b1*vv;
            A[2][v] += b2*vv;
        }
    }

    // term2: B[m][v] = sum_u n2[s,u,m]*V3[u,v]
    float B[5][7];
#pragma unroll
    for (int m = 0; m < 5; ++m)
#pragma unroll
        for (int v = 0; v < 7; ++v) B[m][v] = 0.f;
    const float* n2s = n2 + (size_t)s*80;
    for (int u = 0; u < 16; ++u) {
        const float b0 = n2s[u*5+0];
        const float b1 = n2s[u*5+1];
        const float b2 = n2s[u*5+2];
        const float b3 = n2s[u*5+3];
        const float b4 = n2s[u*5+4];
        const float* vr = V3 + u*7;
#pragma unroll
        for (int v = 0; v < 7; ++v) {
            const float vv = vr[v];
            B[0][v] += b0*vv;
            B[1][v] += b1*vv;
            B[2][v] += b2*vv;
            B[3][v] += b3*vv;
            B[4][v] += b4*vv;
        }
    }

    const float r2 = px*px + py*py + pz*pz;
    const float sh1v[3] = {1.7320508f*px, 1.7320508f*py, 1.7320508f*pz};
    const float sh2v[5] = {3.8729833f*px*py,
                           3.8729833f*py*pz,
                           0.5f*2.2360680f*(3.f*pz*pz - r2),
                           3.8729833f*px*pz,
                           0.5f*3.8729833f*(px*px - py*py)};

    float g1 = 0.f;
#pragma unroll
    for (int m = 0; m < 3; ++m) {
        float t = 0.f;
#pragma unroll
        for (int v = 0; v < 7; ++v) t += ea[v]*A[m][v];
        g1 += sh1v[m]*t;
    }
    float g2 = 0.f;
#pragma unroll
    for (int m = 0; m < 5; ++m) {
        float t = 0.f;
#pragma unroll
        for (int v = 0; v < 7; ++v) t += ea[v]*B[m][v];
        g2 += sh2v[m]*t;
    }

    const float g = 0.04724556f*g0 + 0.04454354f*g1 + 0.04225771f*g2;
    unsafeAtomicAdd(&node_out[d], g);
}

__global__ __launch_bounds__(256) void k_phase3(
    const float* __restrict__ node_out,
    const int* __restrict__ batch,
    float* __restrict__ out)
{
    const int i = blockIdx.x * blockDim.x + threadIdx.x;
    if (i >= NN) return;
    unsafeAtomicAdd(&out[batch[i]], node_out[i]);
}

extern "C" void kernel_launch(void* const* d_in, const int* in_sizes, int n_in,
                              void* d_out, int out_size, void* d_ws, size_t ws_size,
                              hipStream_t stream)
{
    const float* pos  = (const float*)d_in[0];
    const float* x    = (const float*)d_in[1];
    const float* eag  = (const float*)d_in[2];
    const int*   eidx = (const int*)d_in[3];
    const int*   batch= (const int*)d_in[4];
    const float* W1   = (const float*)d_in[5];
    const float* W2   = (const float*)d_in[6];
    const float* W3   = (const float*)d_in[7];
    const float* V1   = (const float*)d_in[8];
    const float* V2   = (const float*)d_in[9];
    const float* V3   = (const float*)d_in[10];
    const int* esrc = eidx;
    const int* edst = eidx + NE;

    float* n0 = (float*)d_ws;                    // NN*64
    float* n1 = n0 + (size_t)NN*64;              // NN*72  [w][m]
    float* n2 = n1 + (size_t)NN*72;              // NN*80  [w][m]
    float* node_out = n2 + (size_t)NN*80;        // NN

    hipMemsetAsync(d_ws, 0, (size_t)NN*217*sizeof(float), stream);
    hipMemsetAsync(d_out, 0, (size_t)NG*sizeof(float), stream);

    k_phase1<<<NE/256, 256, 0, stream>>>(pos, x, eag, esrc, edst, W1, W2, W3, n0, n1, n2);
    k_phase2<<<NE/256, 256, 0, stream>>>(pos, eag, esrc, edst, V1, V2, V3, n0, n1, n2, node_out);
    k_phase3<<<(NN+255)/256, 256, 0, stream>>>(node_out, batch, (float*)d_out);
}

// Round 2
// 703.666 us; speedup vs baseline: 5.4400x; 5.4400x over previous
//
#include <hip/hip_runtime.h>

#define NN 20000
#define NE 320000
#define NG 256
// NA=23, NB=7, M0=64, M1=24, M2=16
// h-row layout (112 floats): [a1*h1[64] | a1*h2[24] | a1*h3[16] | sh1[3] | sh2[5]]

// ---------------- CSR build ----------------

__global__ __launch_bounds__(256) void k_count(const int* __restrict__ edst,
                                               int* __restrict__ deg)
{
    const int e = blockIdx.x * blockDim.x + threadIdx.x;
    if (e >= NE) return;
    atomicAdd(&deg[edst[e]], 1);
}

__global__ __launch_bounds__(1024) void k_scan(const int* __restrict__ deg,
                                               int* __restrict__ offs,
                                               int* __restrict__ cursor)
{
    __shared__ int part[1024];
    const int t = threadIdx.x;
    const int CH = (NN + 1023) / 1024;  // 20
    const int base = t * CH;
    int s = 0;
    for (int i = 0; i < CH; ++i) {
        const int j = base + i;
        if (j < NN) s += deg[j];
    }
    part[t] = s;
    __syncthreads();
    // inclusive Hillis-Steele scan
    for (int off = 1; off < 1024; off <<= 1) {
        int v = 0;
        if (t >= off) v = part[t - off];
        __syncthreads();
        if (t >= off) part[t] += v;
        __syncthreads();
    }
    int run = (t > 0) ? part[t - 1] : 0;  // exclusive prefix for this chunk
    for (int i = 0; i < CH; ++i) {
        const int j = base + i;
        if (j < NN) {
            offs[j] = run;
            cursor[j] = run;
            run += deg[j];
        }
    }
    if (t == 1023) offs[NN] = run;  // == NE
}

__global__ __launch_bounds__(256) void k_fill(const int* __restrict__ edst,
                                              int* __restrict__ cursor,
                                              int* __restrict__ eids)
{
    const int e = blockIdx.x * blockDim.x + threadIdx.x;
    if (e >= NE) return;
    const int p = atomicAdd(&cursor[edst[e]], 1);
    eids[p] = e;
}

// ---------------- phase 1a: per-edge h (no atomics) ----------------

__global__ __launch_bounds__(256) void k_edge_h(
    const float* __restrict__ pos,
    const float* __restrict__ x,
    const float* __restrict__ eag,
    const int* __restrict__ esrc,
    const int* __restrict__ edst,
    const float* __restrict__ W1,
    const float* __restrict__ W2,
    const float* __restrict__ W3,
    float* __restrict__ hbuf)
{
    const int e = blockIdx.x * blockDim.x + threadIdx.x;
    if (e >= NE) return;
    const int s = esrc[e];
    const int d = edst[e];
    const float px = pos[3*s+0] - pos[3*d+0];
    const float py = pos[3*s+1] - pos[3*d+1];
    const float pz = pos[3*s+2] - pos[3*d+2];

    float ea[7];
#pragma unroll
    for (int v = 0; v < 7; ++v) ea[v] = eag[e*7 + v];

    float h1[64], h2[24], h3[16];
#pragma unroll
    for (int w = 0; w < 64; ++w) h1[w] = 0.f;
#pragma unroll
    for (int w = 0; w < 24; ++w) h2[w] = 0.f;
#pragma unroll
    for (int w = 0; w < 16; ++w) h3[w] = 0.f;

    for (int u = 0; u < 23; ++u) {
        const float xu = x[s*23 + u];
#pragma unroll
        for (int v = 0; v < 7; ++v) {
            const float p = xu * ea[v];
            const int base = u*7 + v;
            const float4* w1 = (const float4*)(W1 + base*64);
#pragma unroll
            for (int q = 0; q < 16; ++q) {
                const float4 wv = w1[q];
                h1[4*q+0] += p * wv.x;
                h1[4*q+1] += p * wv.y;
                h1[4*q+2] += p * wv.z;
                h1[4*q+3] += p * wv.w;
            }
            const float4* w2 = (const float4*)(W2 + base*24);
#pragma unroll
            for (int q = 0; q < 6; ++q) {
                const float4 wv = w2[q];
                h2[4*q+0] += p * wv.x;
                h2[4*q+1] += p * wv.y;
                h2[4*q+2] += p * wv.z;
                h2[4*q+3] += p * wv.w;
            }
            const float4* w3 = (const float4*)(W3 + base*16);
#pragma unroll
            for (int q = 0; q < 4; ++q) {
                const float4 wv = w3[q];
                h3[4*q+0] += p * wv.x;
                h3[4*q+1] += p * wv.y;
                h3[4*q+2] += p * wv.z;
                h3[4*q+3] += p * wv.w;
            }
        }
    }

    const float r2 = px*px + py*py + pz*pz;
    const float sh1v[3] = {1.7320508f*px, 1.7320508f*py, 1.7320508f*pz};
    const float sh2v[5] = {3.8729833f*px*py,
                           3.8729833f*py*pz,
                           0.5f*2.2360680f*(3.f*pz*pz - r2),
                           3.8729833f*px*pz,
                           0.5f*3.8729833f*(px*px - py*py)};
    const float a1 = 0.07881104f;  // 1/sqrt(23*7)

    float4* hr = (float4*)(hbuf + (size_t)e * 112);
#pragma unroll
    for (int q = 0; q < 16; ++q)
        hr[q] = make_float4(a1*h1[4*q+0], a1*h1[4*q+1], a1*h1[4*q+2], a1*h1[4*q+3]);
#pragma unroll
    for (int q = 0; q < 6; ++q)
        hr[16+q] = make_float4(a1*h2[4*q+0], a1*h2[4*q+1], a1*h2[4*q+2], a1*h2[4*q+3]);
#pragma unroll
    for (int q = 0; q < 4; ++q)
        hr[22+q] = make_float4(a1*h3[4*q+0], a1*h3[4*q+1], a1*h3[4*q+2], a1*h3[4*q+3]);
    hr[26] = make_float4(sh1v[0], sh1v[1], sh1v[2], sh2v[0]);
    hr[27] = make_float4(sh2v[1], sh2v[2], sh2v[3], sh2v[4]);
}

// ---------------- phase 1b: CSR gather segment-sum (no atomics) ----------------

__global__ __launch_bounds__(256) void k_segsum(
    const float* __restrict__ hbuf,
    const int* __restrict__ offs,
    const int* __restrict__ eids,
    float* __restrict__ n0,
    float* __restrict__ n1,
    float* __restrict__ n2)
{
    const int node = blockIdx.x;
    const int t = threadIdx.x;
    __shared__ float rows[4][112];

    const int beg = offs[node];
    const int end = offs[node + 1];

    // component mapping (uniform per thread, computed once)
    int kind, wi = 0, mi = 0;
    if (t < 64) { kind = 0; }
    else if (t < 136) { const int idx = t - 64; wi = idx / 3; mi = idx - 3*wi; kind = 1; }
    else if (t < 216) { const int idx = t - 136; wi = idx / 5; mi = idx - 5*wi; kind = 2; }
    else kind = 3;

    float acc = 0.f;
    for (int j = beg; j < end; j += 4) {
        const int cnt = min(4, end - j);
        __syncthreads();
        if (t < 28 * cnt) {
            const int r = t / 28, q = t - 28*r;
            const int e = eids[j + r];
            ((float4*)rows[r])[q] = ((const float4*)(hbuf + (size_t)e * 112))[q];
        }
        __syncthreads();
        for (int r = 0; r < cnt; ++r) {
            const float* row = rows[r];
            if (kind == 0)      acc += row[t];
            else if (kind == 1) acc += row[64 + wi] * row[104 + mi];
            else if (kind == 2) acc += row[88 + wi] * row[107 + mi];
        }
    }

    if (kind == 0)      n0[(size_t)node*64 + t] = acc;
    else if (kind == 1) n1[(size_t)node*72 + (t - 64)] = acc;
    else if (kind == 2) n2[(size_t)node*80 + (t - 136)] = acc;
}

// ---------------- phase 2: per-edge g + scatter to node_out ----------------

__global__ __launch_bounds__(256) void k_phase2(
    const float* __restrict__ pos,
    const float* __restrict__ eag,
    const int* __restrict__ esrc,
    const int* __restrict__ edst,
    const float* __restrict__ V1,
    const float* __restrict__ V2,
    const float* __restrict__ V3,
    const float* __restrict__ n0,
    const float* __restrict__ n1,
    const float* __restrict__ n2,
    float* __restrict__ node_out)
{
    const int e = blockIdx.x * blockDim.x + threadIdx.x;
    if (e >= NE) return;
    const int s = esrc[e];
    const int d = edst[e];
    const float px = pos[3*s+0] - pos[3*d+0];
    const float py = pos[3*s+1] - pos[3*d+1];
    const float pz = pos[3*s+2] - pos[3*d+2];

    float ea[7];
#pragma unroll
    for (int v = 0; v < 7; ++v) ea[v] = eag[e*7 + v];

    float r0[7];
#pragma unroll
    for (int v = 0; v < 7; ++v) r0[v] = 0.f;
    const float* n0s = n0 + (size_t)s*64;
    for (int u = 0; u < 64; ++u) {
        const float nu = n0s[u];
        const float* vr = V1 + u*7;
#pragma unroll
        for (int v = 0; v < 7; ++v) r0[v] += nu * vr[v];
    }
    float g0 = 0.f;
#pragma unroll
    for (int v = 0; v < 7; ++v) g0 += ea[v]*r0[v];

    float A[3][7];
#pragma unroll
    for (int m = 0; m < 3; ++m)
#pragma unroll
        for (int v = 0; v < 7; ++v) A[m][v] = 0.f;
    const float* n1s = n1 + (size_t)s*72;
    for (int u = 0; u < 24; ++u) {
        const float b0 = n1s[u*3+0];
        const float b1 = n1s[u*3+1];
        const float b2 = n1s[u*3+2];
        const float* vr = V2 + u*7;
#pragma unroll
        for (int v = 0; v < 7; ++v) {
            const float vv = vr[v];
            A[0][v] += b0*vv;
            A[1][v] += b1*vv;
            A[2][v] += b2*vv;
        }
    }

    float B[5][7];
#pragma unroll
    for (int m = 0; m < 5; ++m)
#pragma unroll
        for (int v = 0; v < 7; ++v) B[m][v] = 0.f;
    const float* n2s = n2 + (size_t)s*80;
    for (int u = 0; u < 16; ++u) {
        const float b0 = n2s[u*5+0];
        const float b1 = n2s[u*5+1];
        const float b2 = n2s[u*5+2];
        const float b3 = n2s[u*5+3];
        const float b4 = n2s[u*5+4];
        const float* vr = V3 + u*7;
#pragma unroll
        for (int v = 0; v < 7; ++v) {
            const float vv = vr[v];
            B[0][v] += b0*vv;
            B[1][v] += b1*vv;
            B[2][v] += b2*vv;
            B[3][v] += b3*vv;
            B[4][v] += b4*vv;
        }
    }

    const float r2 = px*px + py*py + pz*pz;
    const float sh1v[3] = {1.7320508f*px, 1.7320508f*py, 1.7320508f*pz};
    const float sh2v[5] = {3.8729833f*px*py,
                           3.8729833f*py*pz,
                           0.5f*2.2360680f*(3.f*pz*pz - r2),
                           3.8729833f*px*pz,
                           0.5f*3.8729833f*(px*px - py*py)};

    float g1 = 0.f;
#pragma unroll
    for (int m = 0; m < 3; ++m) {
        float t = 0.f;
#pragma unroll
        for (int v = 0; v < 7; ++v) t += ea[v]*A[m][v];
        g1 += sh1v[m]*t;
    }
    float g2 = 0.f;
#pragma unroll
    for (int m = 0; m < 5; ++m) {
        float t = 0.f;
#pragma unroll
        for (int v = 0; v < 7; ++v) t += ea[v]*B[m][v];
        g2 += sh2v[m]*t;
    }

    const float g = 0.04724556f*g0 + 0.04454354f*g1 + 0.04225771f*g2;
    unsafeAtomicAdd(&node_out[d], g);
}

__global__ __launch_bounds__(256) void k_phase3(
    const float* __restrict__ node_out,
    const int* __restrict__ batch,
    float* __restrict__ out)
{
    const int i = blockIdx.x * blockDim.x + threadIdx.x;
    if (i >= NN) return;
    unsafeAtomicAdd(&out[batch[i]], node_out[i]);
}

extern "C" void kernel_launch(void* const* d_in, const int* in_sizes, int n_in,
                              void* d_out, int out_size, void* d_ws, size_t ws_size,
                              hipStream_t stream)
{
    const float* pos  = (const float*)d_in[0];
    const float* x    = (const float*)d_in[1];
    const float* eag  = (const float*)d_in[2];
    const int*   eidx = (const int*)d_in[3];
    const int*   batch= (const int*)d_in[4];
    const float* W1   = (const float*)d_in[5];
    const float* W2   = (const float*)d_in[6];
    const float* W3   = (const float*)d_in[7];
    const float* V1   = (const float*)d_in[8];
    const float* V2   = (const float*)d_in[9];
    const float* V3   = (const float*)d_in[10];
    const int* esrc = eidx;
    const int* edst = eidx + NE;

    // workspace layout (256B-aligned regions); total ~162.5 MB < 256 MiB
    char* ws = (char*)d_ws;
    size_t off = 0;
    auto alloc = [&](size_t bytes) -> void* {
        void* p = ws + off;
        off = (off + bytes + 255) & ~(size_t)255;
        return p;
    };
    float* hbuf     = (float*)alloc((size_t)NE * 112 * sizeof(float));  // 143.36 MB
    float* n0       = (float*)alloc((size_t)NN * 64 * sizeof(float));
    float* n1       = (float*)alloc((size_t)NN * 72 * sizeof(float));
    float* n2       = (float*)alloc((size_t)NN * 80 * sizeof(float));
    float* node_out = (float*)alloc((size_t)NN * sizeof(float));
    int*   deg      = (int*)alloc((size_t)NN * sizeof(int));
    int*   offs     = (int*)alloc((size_t)(NN + 1) * sizeof(int));
    int*   cursor   = (int*)alloc((size_t)NN * sizeof(int));
    int*   eids     = (int*)alloc((size_t)NE * sizeof(int));

    hipMemsetAsync(deg, 0, (size_t)NN * sizeof(int), stream);
    hipMemsetAsync(node_out, 0, (size_t)NN * sizeof(float), stream);
    hipMemsetAsync(d_out, 0, (size_t)NG * sizeof(float), stream);

    k_count<<<NE/256, 256, 0, stream>>>(edst, deg);
    k_scan<<<1, 1024, 0, stream>>>(deg, offs, cursor);
    k_fill<<<NE/256, 256, 0, stream>>>(edst, cursor, eids);
    k_edge_h<<<NE/256, 256, 0, stream>>>(pos, x, eag, esrc, edst, W1, W2, W3, hbuf);
    k_segsum<<<NN, 256, 0, stream>>>(hbuf, offs, eids, n0, n1, n2);
    k_phase2<<<NE/256, 256, 0, stream>>>(pos, eag, esrc, edst, V1, V2, V3, n0, n1, n2, node_out);
    k_phase3<<<(NN+255)/256, 256, 0, stream>>>(node_out, batch, (float*)d_out);
}

// Round 3
// 436.978 us; speedup vs baseline: 8.7600x; 1.6103x over previous
//
#include <hip/hip_runtime.h>

#define NN 20000
#define NE 320000
#define NG 256
#define EB 64          // edges per block in k_edge_h
#define NK 161         // 23*7
#define NW 104         // 64+24+16
// hbuf row (112 floats): [a1*h1[64] | a1*h2[24] | a1*h3[16] | sh1[3] | sh2[5]]

// ---------------- CSR build ----------------

__global__ __launch_bounds__(256) void k_count(const int* __restrict__ edst,
                                               int* __restrict__ deg)
{
    const int e = blockIdx.x * blockDim.x + threadIdx.x;
    if (e >= NE) return;
    atomicAdd(&deg[edst[e]], 1);
}

__global__ __launch_bounds__(1024) void k_scan(const int* __restrict__ deg,
                                               int* __restrict__ offs,
                                               int* __restrict__ cursor)
{
    __shared__ int part[1024];
    const int t = threadIdx.x;
    const int CH = (NN + 1023) / 1024;  // 20
    const int base = t * CH;
    int s = 0;
    for (int i = 0; i < CH; ++i) {
        const int j = base + i;
        if (j < NN) s += deg[j];
    }
    part[t] = s;
    __syncthreads();
    for (int off = 1; off < 1024; off <<= 1) {
        int v = 0;
        if (t >= off) v = part[t - off];
        __syncthreads();
        if (t >= off) part[t] += v;
        __syncthreads();
    }
    int run = (t > 0) ? part[t - 1] : 0;
    for (int i = 0; i < CH; ++i) {
        const int j = base + i;
        if (j < NN) {
            offs[j] = run;
            cursor[j] = run;
            run += deg[j];
        }
    }
    if (t == 1023) offs[NN] = run;
}

__global__ __launch_bounds__(256) void k_fill(const int* __restrict__ edst,
                                              int* __restrict__ cursor,
                                              int* __restrict__ eids)
{
    const int e = blockIdx.x * blockDim.x + threadIdx.x;
    if (e >= NE) return;
    const int p = atomicAdd(&cursor[edst[e]], 1);
    eids[p] = e;
}

// ---------------- Wc = a1 * [W1 | W2 | W3], row-major [k][104] ----------------

__global__ __launch_bounds__(256) void k_build_wc(const float* __restrict__ W1,
                                                  const float* __restrict__ W2,
                                                  const float* __restrict__ W3,
                                                  float* __restrict__ Wc)
{
    const int idx = blockIdx.x * 256 + threadIdx.x;
    if (idx >= NK * NW) return;
    const int k = idx / NW, c = idx - k * NW;
    float v;
    if (c < 64)      v = W1[k*64 + c];
    else if (c < 88) v = W2[k*24 + (c - 64)];
    else             v = W3[k*16 + (c - 88)];
    Wc[idx] = 0.07881104f * v;  // a1 = 1/sqrt(23*7) folded in
}

// ---------------- phase 1a: per-edge h, wave-sliced outputs ----------------
// Block = 4 waves over the SAME 64 edges; wave w computes outputs [26w,26w+26).
// W reads are wave-uniform -> scalar loads (SGPR operand of v_fmac).

__global__ __launch_bounds__(256) void k_edge_h(
    const float* __restrict__ pos,
    const float* __restrict__ x,
    const float* __restrict__ eag,
    const int* __restrict__ esrc,
    const int* __restrict__ edst,
    const float* __restrict__ Wc,
    float* __restrict__ hbuf)
{
    __shared__ int s_lds[EB];
    __shared__ float xa[EB][23];   // bank stride 23 (odd) -> 2-way, free

    const int base = blockIdx.x * EB;
    const int t = threadIdx.x;
    const int lane = t & 63;
    const int wslice = __builtin_amdgcn_readfirstlane(t >> 6);

    if (t < EB) s_lds[t] = esrc[base + t];
    __syncthreads();

    // stage x rows for the block's 64 edges
    for (int i = t; i < EB * 23; i += 256) {
        const int e = i / 23, u = i - e * 23;
        xa[e][u] = x[(size_t)s_lds[e] * 23 + u];
    }

    // wave 1 computes sh for the 64 edges (independent global writes)
    if (t >= 64 && t < 128) {
        const int L = t - 64;
        const int eg = base + L;
        const int s = s_lds[L], d = edst[eg];
        const float px = pos[3*s+0] - pos[3*d+0];
        const float py = pos[3*s+1] - pos[3*d+1];
        const float pz = pos[3*s+2] - pos[3*d+2];
        const float r2 = px*px + py*py + pz*pz;
        float* o = hbuf + (size_t)eg * 112 + 104;
        o[0] = 1.7320508f*px;
        o[1] = 1.7320508f*py;
        o[2] = 1.7320508f*pz;
        o[3] = 3.8729833f*px*py;
        o[4] = 3.8729833f*py*pz;
        o[5] = 1.1180340f*(3.f*pz*pz - r2);
        o[6] = 3.8729833f*px*pz;
        o[7] = 1.9364917f*(px*px - py*py);
    }
    __syncthreads();

    const int eg = base + lane;
    float ea[7];
#pragma unroll
    for (int v = 0; v < 7; ++v) ea[v] = eag[(size_t)eg * 7 + v];

    float acc[26];
#pragma unroll
    for (int j = 0; j < 26; ++j) acc[j] = 0.f;

    const float* __restrict__ wbase = Wc + 26 * wslice;
    for (int u = 0; u < 23; ++u) {
        const float xu = xa[lane][u];
#pragma unroll
        for (int v = 0; v < 7; ++v) {
            const float p = xu * ea[v];
            const float* __restrict__ wk = wbase + (u*7 + v) * NW;  // uniform addr
#pragma unroll
            for (int j = 0; j < 26; ++j) acc[j] += p * wk[j];
        }
    }

    float* o = hbuf + (size_t)eg * 112 + 26 * wslice;
#pragma unroll
    for (int j = 0; j < 26; ++j) o[j] = acc[j];
}

// ---------------- phase 1b: CSR gather segment-sum (no atomics) ----------------

__global__ __launch_bounds__(256) void k_segsum(
    const float* __restrict__ hbuf,
    const int* __restrict__ offs,
    const int* __restrict__ eids,
    float* __restrict__ n0,
    float* __restrict__ n1,
    float* __restrict__ n2)
{
    const int node = blockIdx.x;
    const int t = threadIdx.x;
    __shared__ float rows[4][112];

    const int beg = offs[node];
    const int end = offs[node + 1];

    int kind, wi = 0, mi = 0;
    if (t < 64) { kind = 0; }
    else if (t < 136) { const int idx = t - 64; wi = idx / 3; mi = idx - 3*wi; kind = 1; }
    else if (t < 216) { const int idx = t - 136; wi = idx / 5; mi = idx - 5*wi; kind = 2; }
    else kind = 3;

    float acc = 0.f;
    for (int j = beg; j < end; j += 4) {
        const int cnt = min(4, end - j);
        __syncthreads();
        if (t < 28 * cnt) {
            const int r = t / 28, q = t - 28*r;
            const int e = eids[j + r];
            ((float4*)rows[r])[q] = ((const float4*)(hbuf + (size_t)e * 112))[q];
        }
        __syncthreads();
        for (int r = 0; r < cnt; ++r) {
            const float* row = rows[r];
            if (kind == 0)      acc += row[t];
            else if (kind == 1) acc += row[64 + wi] * row[104 + mi];
            else if (kind == 2) acc += row[88 + wi] * row[107 + mi];
        }
    }

    if (kind == 0)      n0[(size_t)node*64 + t] = acc;
    else if (kind == 1) n1[(size_t)node*72 + (t - 64)] = acc;
    else if (kind == 2) n2[(size_t)node*80 + (t - 136)] = acc;
}

// ---------------- phase 2: per-edge g + scatter to node_out ----------------

__global__ __launch_bounds__(256) void k_phase2(
    const float* __restrict__ pos,
    const float* __restrict__ eag,
    const int* __restrict__ esrc,
    const int* __restrict__ edst,
    const float* __restrict__ V1,
    const float* __restrict__ V2,
    const float* __restrict__ V3,
    const float* __restrict__ n0,
    const float* __restrict__ n1,
    const float* __restrict__ n2,
    float* __restrict__ node_out)
{
    const int e = blockIdx.x * blockDim.x + threadIdx.x;
    if (e >= NE) return;
    const int s = esrc[e];
    const int d = edst[e];
    const float px = pos[3*s+0] - pos[3*d+0];
    const float py = pos[3*s+1] - pos[3*d+1];
    const float pz = pos[3*s+2] - pos[3*d+2];

    float ea[7];
#pragma unroll
    for (int v = 0; v < 7; ++v) ea[v] = eag[e*7 + v];

    // term0
    float r0[7];
#pragma unroll
    for (int v = 0; v < 7; ++v) r0[v] = 0.f;
    const float4* n0s = (const float4*)(n0 + (size_t)s * 64);
#pragma unroll
    for (int q = 0; q < 16; ++q) {
        const float4 c = n0s[q];
        const float cf[4] = {c.x, c.y, c.z, c.w};
#pragma unroll
        for (int j = 0; j < 4; ++j) {
            const int u = 4*q + j;
            const float* vr = V1 + u*7;
#pragma unroll
            for (int v = 0; v < 7; ++v) r0[v] += cf[j] * vr[v];
        }
    }
    float g0 = 0.f;
#pragma unroll
    for (int v = 0; v < 7; ++v) g0 += ea[v] * r0[v];

    // term1: A[m][v] = sum_u n1[s,u,m]*V2[u,v]   (n1 row = [u][m], 72 floats)
    float A[3][7];
#pragma unroll
    for (int m = 0; m < 3; ++m)
#pragma unroll
        for (int v = 0; v < 7; ++v) A[m][v] = 0.f;
    const float4* n1s = (const float4*)(n1 + (size_t)s * 72);
#pragma unroll
    for (int q = 0; q < 18; ++q) {
        const float4 c = n1s[q];
        const float cf[4] = {c.x, c.y, c.z, c.w};
#pragma unroll
        for (int j = 0; j < 4; ++j) {
            const int i = 4*q + j;
            const int u = i / 3, m = i - 3*u;
            const float* vr = V2 + u*7;
#pragma unroll
            for (int v = 0; v < 7; ++v) A[m][v] += cf[j] * vr[v];
        }
    }

    // term2: B[m][v] = sum_u n2[s,u,m]*V3[u,v]   (n2 row = [u][m], 80 floats)
    float B[5][7];
#pragma unroll
    for (int m = 0; m < 5; ++m)
#pragma unroll
        for (int v = 0; v < 7; ++v) B[m][v] = 0.f;
    const float4* n2s = (const float4*)(n2 + (size_t)s * 80);
#pragma unroll
    for (int q = 0; q < 20; ++q) {
        const float4 c = n2s[q];
        const float cf[4] = {c.x, c.y, c.z, c.w};
#pragma unroll
        for (int j = 0; j < 4; ++j) {
            const int i = 4*q + j;
            const int u = i / 5, m = i - 5*u;
            const float* vr = V3 + u*7;
#pragma unroll
            for (int v = 0; v < 7; ++v) B[m][v] += cf[j] * vr[v];
        }
    }

    const float r2 = px*px + py*py + pz*pz;
    const float sh1v[3] = {1.7320508f*px, 1.7320508f*py, 1.7320508f*pz};
    const float sh2v[5] = {3.8729833f*px*py,
                           3.8729833f*py*pz,
                           1.1180340f*(3.f*pz*pz - r2),
                           3.8729833f*px*pz,
                           1.9364917f*(px*px - py*py)};

    float g1 = 0.f;
#pragma unroll
    for (int m = 0; m < 3; ++m) {
        float tt = 0.f;
#pragma unroll
        for (int v = 0; v < 7; ++v) tt += ea[v] * A[m][v];
        g1 += sh1v[m] * tt;
    }
    float g2 = 0.f;
#pragma unroll
    for (int m = 0; m < 5; ++m) {
        float tt = 0.f;
#pragma unroll
        for (int v = 0; v < 7; ++v) tt += ea[v] * B[m][v];
        g2 += sh2v[m] * tt;
    }

    const float g = 0.04724556f*g0 + 0.04454354f*g1 + 0.04225771f*g2;
    unsafeAtomicAdd(&node_out[d], g);
}

__global__ __launch_bounds__(256) void k_phase3(
    const float* __restrict__ node_out,
    const int* __restrict__ batch,
    float* __restrict__ out)
{
    const int i = blockIdx.x * blockDim.x + threadIdx.x;
    if (i >= NN) return;
    unsafeAtomicAdd(&out[batch[i]], node_out[i]);
}

extern "C" void kernel_launch(void* const* d_in, const int* in_sizes, int n_in,
                              void* d_out, int out_size, void* d_ws, size_t ws_size,
                              hipStream_t stream)
{
    const float* pos  = (const float*)d_in[0];
    const float* x    = (const float*)d_in[1];
    const float* eag  = (const float*)d_in[2];
    const int*   eidx = (const int*)d_in[3];
    const int*   batch= (const int*)d_in[4];
    const float* W1   = (const float*)d_in[5];
    const float* W2   = (const float*)d_in[6];
    const float* W3   = (const float*)d_in[7];
    const float* V1   = (const float*)d_in[8];
    const float* V2   = (const float*)d_in[9];
    const float* V3   = (const float*)d_in[10];
    const int* esrc = eidx;
    const int* edst = eidx + NE;

    char* ws = (char*)d_ws;
    size_t off = 0;
    auto alloc = [&](size_t bytes) -> void* {
        void* p = ws + off;
        off = (off + bytes + 255) & ~(size_t)255;
        return p;
    };
    float* hbuf     = (float*)alloc((size_t)NE * 112 * sizeof(float));  // 143.36 MB
    float* n0       = (float*)alloc((size_t)NN * 64 * sizeof(float));
    float* n1       = (float*)alloc((size_t)NN * 72 * sizeof(float));
    float* n2       = (float*)alloc((size_t)NN * 80 * sizeof(float));
    float* node_out = (float*)alloc((size_t)NN * sizeof(float));
    int*   deg      = (int*)alloc((size_t)NN * sizeof(int));
    int*   offs     = (int*)alloc((size_t)(NN + 1) * sizeof(int));
    int*   cursor   = (int*)alloc((size_t)NN * sizeof(int));
    int*   eids     = (int*)alloc((size_t)NE * sizeof(int));
    float* Wc       = (float*)alloc((size_t)NK * NW * sizeof(float));   // 67 KB

    hipMemsetAsync(deg, 0, (size_t)NN * sizeof(int), stream);
    hipMemsetAsync(node_out, 0, (size_t)NN * sizeof(float), stream);
    hipMemsetAsync(d_out, 0, (size_t)NG * sizeof(float), stream);

    k_build_wc<<<(NK*NW + 255)/256, 256, 0, stream>>>(W1, W2, W3, Wc);
    k_count<<<NE/256, 256, 0, stream>>>(edst, deg);
    k_scan<<<1, 1024, 0, stream>>>(deg, offs, cursor);
    k_fill<<<NE/256, 256, 0, stream>>>(edst, cursor, eids);
    k_edge_h<<<NE/EB, 256, 0, stream>>>(pos, x, eag, esrc, edst, Wc, hbuf);
    k_segsum<<<NN, 256, 0, stream>>>(hbuf, offs, eids, n0, n1, n2);
    k_phase2<<<NE/256, 256, 0, stream>>>(pos, eag, esrc, edst, V1, V2, V3, n0, n1, n2, node_out);
    k_phase3<<<(NN+255)/256, 256, 0, stream>>>(node_out, batch, (float*)d_out);
}

// Round 4
// 427.750 us; speedup vs baseline: 8.9490x; 1.0216x over previous
//
#include <hip/hip_runtime.h>

#define NN 20000
#define NE 320000
#define NG 256
#define NZ 728            // 7*104
#define NH 104            // 64+24+16
#define NCOMP 216         // 64 + 24*3 + 16*5

static __device__ __forceinline__ float bf2f(unsigned short u) {
    unsigned int x = ((unsigned int)u) << 16;
    union { unsigned int i; float f; } c; c.i = x; return c.f;
}
static __device__ __forceinline__ unsigned short f2bf(float f) {
    union { float f; unsigned int i; } c; c.f = f;
    unsigned int x = c.i;
    return (unsigned short)((x + 0x7FFFu + ((x >> 16) & 1u)) >> 16);
}
static __device__ __forceinline__ void unpk2(unsigned int w, float& a, float& b) {
    union { unsigned int i; float f; } c0, c1;
    c0.i = w << 16; c1.i = w & 0xFFFF0000u;
    a = c0.f; b = c1.f;
}

// ---------------- Wz = a1 * concat(W1,W2,W3) as [u][v*104+w] ----------------

__global__ __launch_bounds__(256) void k_build_wz(const float* __restrict__ W1,
                                                  const float* __restrict__ W2,
                                                  const float* __restrict__ W3,
                                                  float* __restrict__ Wz)
{
    const int idx = blockIdx.x * 256 + threadIdx.x;  // u*728 + c
    if (idx >= 23 * NZ) return;
    const int u = idx / NZ, c = idx - u * NZ;
    const int v = c / NH, w = c - v * NH;
    float val;
    if (w < 64)      val = W1[(u*7 + v)*64 + w];
    else if (w < 88) val = W2[(u*7 + v)*24 + (w - 64)];
    else             val = W3[(u*7 + v)*16 + (w - 88)];
    Wz[idx] = 0.07881104f * val;   // a1 = 1/sqrt(23*7)
}

// ---------------- dual CSR build ----------------

__global__ __launch_bounds__(256) void k_count2(const int* __restrict__ esrc,
                                                const int* __restrict__ edst,
                                                int* __restrict__ deg_src,
                                                int* __restrict__ deg_dst)
{
    const int e = blockIdx.x * 256 + threadIdx.x;
    if (e >= NE) return;
    atomicAdd(&deg_src[esrc[e]], 1);
    atomicAdd(&deg_dst[edst[e]], 1);
}

__global__ __launch_bounds__(1024) void k_scan2(const int* __restrict__ deg_src,
                                                const int* __restrict__ deg_dst,
                                                int* __restrict__ offs_src,
                                                int* __restrict__ cur_src,
                                                int* __restrict__ offs_dst,
                                                int* __restrict__ cur_dst)
{
    const int* deg = blockIdx.x ? deg_dst : deg_src;
    int* offs = blockIdx.x ? offs_dst : offs_src;
    int* cur  = blockIdx.x ? cur_dst  : cur_src;

    __shared__ int part[1024];
    const int t = threadIdx.x;
    const int CH = (NN + 1023) / 1024;  // 20
    const int base = t * CH;
    int s = 0;
    for (int i = 0; i < CH; ++i) {
        const int j = base + i;
        if (j < NN) s += deg[j];
    }
    part[t] = s;
    __syncthreads();
    for (int off = 1; off < 1024; off <<= 1) {
        int v = 0;
        if (t >= off) v = part[t - off];
        __syncthreads();
        if (t >= off) part[t] += v;
        __syncthreads();
    }
    int run = (t > 0) ? part[t - 1] : 0;
    for (int i = 0; i < CH; ++i) {
        const int j = base + i;
        if (j < NN) {
            offs[j] = run;
            cur[j] = run;
            run += deg[j];
        }
    }
    if (t == 1023) offs[NN] = run;
}

// fill both CSRs; pre-gather ea into src-order, sh into dst-order
__global__ __launch_bounds__(256) void k_fill2(const float* __restrict__ pos,
                                               const float* __restrict__ eag,
                                               const int* __restrict__ esrc,
                                               const int* __restrict__ edst,
                                               int* __restrict__ cur_src,
                                               int* __restrict__ cur_dst,
                                               int* __restrict__ srcq,
                                               int* __restrict__ pq,
                                               float* __restrict__ eaq,
                                               float* __restrict__ sh_csr)
{
    const int e = blockIdx.x * 256 + threadIdx.x;
    if (e >= NE) return;
    const int s = esrc[e], d = edst[e];
    const int q = atomicAdd(&cur_src[s], 1);
    const int p = atomicAdd(&cur_dst[d], 1);
    srcq[q] = s;
    pq[q] = p;
#pragma unroll
    for (int v = 0; v < 7; ++v) eaq[(size_t)q*7 + v] = eag[(size_t)e*7 + v];
    const float px = pos[3*s+0] - pos[3*d+0];
    const float py = pos[3*s+1] - pos[3*d+1];
    const float pz = pos[3*s+2] - pos[3*d+2];
    const float r2 = px*px + py*py + pz*pz;
    float* o = sh_csr + (size_t)p * 8;
    o[0] = 1.7320508f*px;
    o[1] = 1.7320508f*py;
    o[2] = 1.7320508f*pz;
    o[3] = 3.8729833f*px*py;
    o[4] = 3.8729833f*py*pz;
    o[5] = 1.1180340f*(3.f*pz*pz - r2);
    o[6] = 3.8729833f*px*pz;
    o[7] = 1.9364917f*(px*px - py*py);
}

// ---------------- node GEMM: z[n][728] = x[n][23] @ Wz ----------------
// block = 4 waves x 64 nodes; wave w computes comps [182w,182w+182) in 7 chunks of 26

__global__ __launch_bounds__(256) void k_node_z(const float* __restrict__ x,
                                                const float* __restrict__ Wz,
                                                float* __restrict__ z)
{
    __shared__ float xa[64][23];
    const int t = threadIdx.x;
    const int base = blockIdx.x * 64;
    for (int i = t; i < 64*23; i += 256) {
        const int nloc = i / 23, u = i - nloc*23;
        const int n = base + nloc;
        xa[nloc][u] = (n < NN) ? x[(size_t)n*23 + u] : 0.f;
    }
    __syncthreads();
    const int lane = t & 63;
    const int wslice = __builtin_amdgcn_readfirstlane(t >> 6);
    const int node = base + lane;
    for (int ch = 0; ch < 7; ++ch) {
        const int cb = wslice*182 + ch*26;
        float acc[26];
#pragma unroll
        for (int j = 0; j < 26; ++j) acc[j] = 0.f;
        for (int u = 0; u < 23; ++u) {
            const float xu = xa[lane][u];
            const float* __restrict__ wk = Wz + u*NZ + cb;  // uniform -> scalar
#pragma unroll
            for (int j = 0; j < 26; ++j) acc[j] += xu * wk[j];
        }
        if (node < NN) {
            float* o = z + (size_t)node*NZ + cb;
#pragma unroll
            for (int j = 0; j < 26; ++j) o[j] = acc[j];
        }
    }
}

// ---------------- edge contraction: h[e][w] = sum_v ea[v]*z[src][v][w] ----------------
// block per 8 consecutive src nodes; z staged in LDS; 104 threads per edge, 2 edges/iter

__global__ __launch_bounds__(256) void k_edge_hb(const float* __restrict__ z,
                                                 const int* __restrict__ offs_src,
                                                 const int* __restrict__ srcq,
                                                 const int* __restrict__ pq,
                                                 const float* __restrict__ eaq,
                                                 unsigned short* __restrict__ hbuf)
{
    __shared__ float zl[8 * NZ];    // 23296 B
    __shared__ int qrange[2];
    const int t = threadIdx.x;
    const int base = blockIdx.x * 8;
    if (t < 2) qrange[t] = offs_src[base + 8*t];
    const float4* zg = (const float4*)(z + (size_t)base * NZ);
    float4* zl4 = (float4*)zl;
    for (int i = t; i < (8*NZ)/4; i += 256) zl4[i] = zg[i];
    __syncthreads();
    const int qbeg = qrange[0], qend = qrange[1];
    const int sub = t >> 7;
    const int tw = t & 127;
    for (int q0 = qbeg; q0 < qend; q0 += 2) {
        const int q = q0 + sub;
        if (q < qend && tw < NH) {
            const int slot = srcq[q] - base;
            const int p = pq[q];
            const float* zr = zl + slot*NZ + tw;
            const float* ear = eaq + (size_t)q * 7;
            float h = 0.f;
#pragma unroll
            for (int v = 0; v < 7; ++v) h += ear[v] * zr[v*NH];
            hbuf[(size_t)p*NH + tw] = f2bf(h);
        }
    }
}

// ---------------- streaming segment-sum by dst ----------------

__global__ __launch_bounds__(256) void k_segsum(const unsigned short* __restrict__ hbuf,
                                                const float* __restrict__ sh_csr,
                                                const int* __restrict__ offs_dst,
                                                unsigned short* __restrict__ ncat)
{
    const int node = blockIdx.x;
    const int t = threadIdx.x;
    __shared__ uint4 rows4[4][13];   // 4 rows x 104 bf16
    __shared__ float shl[4][8];

    const int beg = offs_dst[node], end = offs_dst[node + 1];

    int kind, wi = 0, mi = 0;
    if (t < 64) kind = 0;
    else if (t < 136) { const int idx = t - 64;  wi = idx / 3; mi = idx - 3*wi; kind = 1; }
    else if (t < 216) { const int idx = t - 136; wi = idx / 5; mi = idx - 5*wi; kind = 2; }
    else kind = 3;

    float acc = 0.f;
    for (int j = beg; j < end; j += 4) {
        const int cnt = min(4, end - j);
        __syncthreads();
        if (t < 13 * cnt) {
            const int r = t / 13, qq = t - 13*r;
            rows4[r][qq] = ((const uint4*)(hbuf + (size_t)(j + r) * NH))[qq];
        } else if (t >= 64 && t < 64 + 8*cnt) {
            const int i = t - 64, r = i / 8, k = i - 8*r;
            shl[r][k] = sh_csr[(size_t)(j + r) * 8 + k];
        }
        __syncthreads();
        for (int r = 0; r < cnt; ++r) {
            const unsigned short* row = (const unsigned short*)rows4[r];
            if (kind == 0)      acc += bf2f(row[t]);
            else if (kind == 1) acc += bf2f(row[64 + wi]) * shl[r][mi];
            else if (kind == 2) acc += bf2f(row[88 + wi]) * shl[r][3 + mi];
        }
    }
    if (t < NCOMP) ncat[(size_t)node * NCOMP + t] = f2bf(acc);
}

// ---------------- phase 2: per-edge g + scatter ----------------
// ncat row: [n0:64 | n1:(w,m) 72 | n2:(w,m) 80] bf16

__global__ __launch_bounds__(256) void k_phase2(const float* __restrict__ pos,
                                                const float* __restrict__ eag,
                                                const int* __restrict__ esrc,
                                                const int* __restrict__ edst,
                                                const float* __restrict__ V1,
                                                const float* __restrict__ V2,
                                                const float* __restrict__ V3,
                                                const unsigned short* __restrict__ ncat,
                                                float* __restrict__ node_out)
{
    const int e = blockIdx.x * 256 + threadIdx.x;
    if (e >= NE) return;
    const int s = esrc[e], d = edst[e];
    float ea[7];
#pragma unroll
    for (int v = 0; v < 7; ++v) ea[v] = eag[(size_t)e*7 + v];
    const float px = pos[3*s+0] - pos[3*d+0];
    const float py = pos[3*s+1] - pos[3*d+1];
    const float pz = pos[3*s+2] - pos[3*d+2];
    const float r2 = px*px + py*py + pz*pz;
    const float sh1v[3] = {1.7320508f*px, 1.7320508f*py, 1.7320508f*pz};
    const float sh2v[5] = {3.8729833f*px*py,
                           3.8729833f*py*pz,
                           1.1180340f*(3.f*pz*pz - r2),
                           3.8729833f*px*pz,
                           1.9364917f*(px*px - py*py)};

    const uint4* nrow = (const uint4*)(ncat + (size_t)s * NCOMP);  // 27 uint4

    float g0 = 0.f, g1 = 0.f, g2 = 0.f;

    // n0: comps 0..63, u = comp; coef = sum_v V1[u,v]*ea[v]
#pragma unroll
    for (int c8 = 0; c8 < 8; ++c8) {
        const uint4 pk = nrow[c8];
        float vals[8];
        unpk2(pk.x, vals[0], vals[1]);
        unpk2(pk.y, vals[2], vals[3]);
        unpk2(pk.z, vals[4], vals[5]);
        unpk2(pk.w, vals[6], vals[7]);
#pragma unroll
        for (int j = 0; j < 8; ++j) {
            const int u = c8*8 + j;
            float cu = 0.f;
#pragma unroll
            for (int v = 0; v < 7; ++v) cu += V2 == V2 ? V1[u*7 + v] * ea[v] : 0.f;
            g0 += vals[j] * cu;
        }
    }

    // n1: 72 values (u,m) m-fastest, u<24
    {
        float cu = 0.f;
#pragma unroll
        for (int c8 = 0; c8 < 9; ++c8) {
            const uint4 pk = nrow[8 + c8];
            float vals[8];
            unpk2(pk.x, vals[0], vals[1]);
            unpk2(pk.y, vals[2], vals[3]);
            unpk2(pk.z, vals[4], vals[5]);
            unpk2(pk.w, vals[6], vals[7]);
#pragma unroll
            for (int j = 0; j < 8; ++j) {
                const int i = c8*8 + j;
                const int u = i / 3, m = i - 3*u;
                if (m == 0) {
                    cu = 0.f;
#pragma unroll
                    for (int v = 0; v < 7; ++v) cu += V2[u*7 + v] * ea[v];
                }
                g1 += vals[j] * sh1v[m] * cu;
            }
        }
    }

    // n2: 80 values (u,m) m-fastest, u<16
    {
        float cu = 0.f;
#pragma unroll
        for (int c8 = 0; c8 < 10; ++c8) {
            const uint4 pk = nrow[17 + c8];
            float vals[8];
            unpk2(pk.x, vals[0], vals[1]);
            unpk2(pk.y, vals[2], vals[3]);
            unpk2(pk.z, vals[4], vals[5]);
            unpk2(pk.w, vals[6], vals[7]);
#pragma unroll
            for (int j = 0; j < 8; ++j) {
                const int i = c8*8 + j;
                const int u = i / 5, m = i - 5*u;
                if (m == 0) {
                    cu = 0.f;
#pragma unroll
                    for (int v = 0; v < 7; ++v) cu += V3[u*7 + v] * ea[v];
                }
                g2 += vals[j] * sh2v[m] * cu;
            }
        }
    }

    const float g = 0.04724556f*g0 + 0.04454354f*g1 + 0.04225771f*g2;
    unsafeAtomicAdd(&node_out[d], g);
}

__global__ __launch_bounds__(256) void k_phase3(const float* __restrict__ node_out,
                                                const int* __restrict__ batch,
                                                float* __restrict__ out)
{
    const int i = blockIdx.x * 256 + threadIdx.x;
    if (i >= NN) return;
    unsafeAtomicAdd(&out[batch[i]], node_out[i]);
}

extern "C" void kernel_launch(void* const* d_in, const int* in_sizes, int n_in,
                              void* d_out, int out_size, void* d_ws, size_t ws_size,
                              hipStream_t stream)
{
    const float* pos  = (const float*)d_in[0];
    const float* x    = (const float*)d_in[1];
    const float* eag  = (const float*)d_in[2];
    const int*   eidx = (const int*)d_in[3];
    const int*   batch= (const int*)d_in[4];
    const float* W1   = (const float*)d_in[5];
    const float* W2   = (const float*)d_in[6];
    const float* W3   = (const float*)d_in[7];
    const float* V1   = (const float*)d_in[8];
    const float* V2   = (const float*)d_in[9];
    const float* V3   = (const float*)d_in[10];
    const int* esrc = eidx;
    const int* edst = eidx + NE;

    char* ws = (char*)d_ws;
    size_t off = 0;
    auto alloc = [&](size_t bytes) -> void* {
        void* p = ws + off;
        off = (off + bytes + 255) & ~(size_t)255;
        return p;
    };
    float* z        = (float*)alloc((size_t)NN * NZ * sizeof(float));        // 58.2 MB
    unsigned short* hbuf = (unsigned short*)alloc((size_t)NE * NH * 2);      // 66.6 MB
    float* sh_csr   = (float*)alloc((size_t)NE * 8 * sizeof(float));         // 10.2 MB
    float* eaq      = (float*)alloc((size_t)NE * 7 * sizeof(float));         // 9.0 MB
    unsigned short* ncat = (unsigned short*)alloc((size_t)NN * NCOMP * 2);   // 8.6 MB
    int*   srcq     = (int*)alloc((size_t)NE * sizeof(int));
    int*   pq       = (int*)alloc((size_t)NE * sizeof(int));
    float* Wz       = (float*)alloc((size_t)23 * NZ * sizeof(float));
    // zero-init region: [deg_src | deg_dst | node_out]
    int*   deg_src  = (int*)alloc((size_t)NN * sizeof(int));
    int*   deg_dst  = (int*)alloc((size_t)NN * sizeof(int));
    float* node_out = (float*)alloc((size_t)NN * sizeof(float));
    int*   offs_src = (int*)alloc((size_t)(NN + 1) * sizeof(int));
    int*   offs_dst = (int*)alloc((size_t)(NN + 1) * sizeof(int));
    int*   cur_src  = (int*)alloc((size_t)NN * sizeof(int));
    int*   cur_dst  = (int*)alloc((size_t)NN * sizeof(int));

    hipMemsetAsync(deg_src, 0, ((char*)offs_src - (char*)deg_src), stream);
    hipMemsetAsync(d_out, 0, (size_t)NG * sizeof(float), stream);

    k_build_wz<<<(23*NZ + 255)/256, 256, 0, stream>>>(W1, W2, W3, Wz);
    k_count2<<<NE/256, 256, 0, stream>>>(esrc, edst, deg_src, deg_dst);
    k_scan2<<<2, 1024, 0, stream>>>(deg_src, deg_dst, offs_src, cur_src, offs_dst, cur_dst);
    k_fill2<<<NE/256, 256, 0, stream>>>(pos, eag, esrc, edst, cur_src, cur_dst,
                                        srcq, pq, eaq, sh_csr);
    k_node_z<<<(NN + 63)/64, 256, 0, stream>>>(x, Wz, z);
    k_edge_hb<<<NN/8, 256, 0, stream>>>(z, offs_src, srcq, pq, eaq, hbuf);
    k_segsum<<<NN, 256, 0, stream>>>(hbuf, sh_csr, offs_dst, ncat);
    k_phase2<<<NE/256, 256, 0, stream>>>(pos, eag, esrc, edst, V1, V2, V3, ncat, node_out);
    k_phase3<<<(NN + 255)/256, 256, 0, stream>>>(node_out, batch, (float*)d_out);
}

// Round 5
// 379.762 us; speedup vs baseline: 10.0798x; 1.1264x over previous
//
#include <hip/hip_runtime.h>

#define NN 20000
#define NE 320000
#define NG 256
#define NZ 728            // 7*104
#define NH 104            // 64+24+16
#define NCOMP 216         // 64 + 24*3 + 16*5

static __device__ __forceinline__ float bf2f(unsigned short u) {
    unsigned int x = ((unsigned int)u) << 16;
    union { unsigned int i; float f; } c; c.i = x; return c.f;
}
static __device__ __forceinline__ unsigned short f2bf(float f) {
    union { float f; unsigned int i; } c; c.f = f;
    unsigned int x = c.i;
    return (unsigned short)((x + 0x7FFFu + ((x >> 16) & 1u)) >> 16);
}
static __device__ __forceinline__ void unpk2(unsigned int w, float& a, float& b) {
    union { unsigned int i; float f; } c0, c1;
    c0.i = w << 16; c1.i = w & 0xFFFF0000u;
    a = c0.f; b = c1.f;
}

// ---------------- K1: blocks [0,1250) count degrees; [1250,1316) build Wz ----------------

__global__ __launch_bounds__(256) void k_count_wz(const int* __restrict__ esrc,
                                                  const int* __restrict__ edst,
                                                  const float* __restrict__ W1,
                                                  const float* __restrict__ W2,
                                                  const float* __restrict__ W3,
                                                  int* __restrict__ deg_src,
                                                  int* __restrict__ deg_dst,
                                                  float* __restrict__ Wz)
{
    const int b = blockIdx.x, t = threadIdx.x;
    if (b < 1250) {
        const int e = b * 256 + t;           // 1250*256 == NE exactly
        atomicAdd(&deg_src[esrc[e]], 1);
        atomicAdd(&deg_dst[edst[e]], 1);
    } else {
        const int idx = (b - 1250) * 256 + t;   // Wz: [u][v*104+w], a1 folded
        if (idx < 23 * NZ) {
            const int u = idx / NZ, c = idx - u * NZ;
            const int v = c / NH, w = c - v * NH;
            float val;
            if (w < 64)      val = W1[(u*7 + v)*64 + w];
            else if (w < 88) val = W2[(u*7 + v)*24 + (w - 64)];
            else             val = W3[(u*7 + v)*16 + (w - 88)];
            Wz[idx] = 0.07881104f * val;     // a1 = 1/sqrt(23*7)
        }
    }
}

// ---------------- K2: blocks 0,1 scan src/dst degrees; blocks 2.. node_z ----------------

__global__ __launch_bounds__(256) void k_scan_nodez(const int* __restrict__ deg_src,
                                                    const int* __restrict__ deg_dst,
                                                    const float* __restrict__ x,
                                                    const float* __restrict__ Wz,
                                                    int* __restrict__ offs_src,
                                                    int* __restrict__ cur_src,
                                                    int* __restrict__ offs_dst,
                                                    int* __restrict__ cur_dst,
                                                    float* __restrict__ z)
{
    __shared__ __align__(16) char smem[64 * 23 * 4];
    const int b = blockIdx.x, t = threadIdx.x;
    if (b < 2) {
        int* part = (int*)smem;
        const int* deg = b ? deg_dst : deg_src;
        int* offs = b ? offs_dst : offs_src;
        int* cur  = b ? cur_dst  : cur_src;
        const int CH = 79;                     // 256*79 >= 20000
        const int base = t * CH;
        int s = 0;
        for (int i = 0; i < CH; ++i) { const int j = base + i; if (j < NN) s += deg[j]; }
        part[t] = s;
        __syncthreads();
        for (int off = 1; off < 256; off <<= 1) {
            int v = 0; if (t >= off) v = part[t - off];
            __syncthreads();
            if (t >= off) part[t] += v;
            __syncthreads();
        }
        int run = t ? part[t - 1] : 0;
        for (int i = 0; i < CH; ++i) {
            const int j = base + i;
            if (j < NN) { offs[j] = run; cur[j] = run; run += deg[j]; }
        }
        if (t == 255) offs[NN] = run;
    } else {
        float (*xa)[23] = (float (*)[23])smem;
        const int base = (b - 2) * 64;
        for (int i = t; i < 64 * 23; i += 256) {
            const int nl = i / 23, u = i - nl * 23;
            const int n = base + nl;
            xa[nl][u] = (n < NN) ? x[(size_t)n * 23 + u] : 0.f;
        }
        __syncthreads();
        const int lane = t & 63;
        const int ws = __builtin_amdgcn_readfirstlane(t >> 6);
        const int node = base + lane;
        for (int ch = 0; ch < 7; ++ch) {
            const int cb = ws * 182 + ch * 26;
            float acc[26];
#pragma unroll
            for (int j = 0; j < 26; ++j) acc[j] = 0.f;
            for (int u = 0; u < 23; ++u) {
                const float xu = xa[lane][u];
                const float* __restrict__ wk = Wz + u * NZ + cb;   // uniform -> scalar
#pragma unroll
                for (int j = 0; j < 26; ++j) acc[j] += xu * wk[j];
            }
            if (node < NN) {
                float* o = z + (size_t)node * NZ + cb;
#pragma unroll
                for (int j = 0; j < 26; ++j) o[j] = acc[j];
            }
        }
    }
}

// ---------------- K3: fill dual CSR; pre-gather ea (stride 8) and sh (dst order) ----------------

__global__ __launch_bounds__(256) void k_fill(const float* __restrict__ pos,
                                              const float* __restrict__ eag,
                                              const int* __restrict__ esrc,
                                              const int* __restrict__ edst,
                                              int* __restrict__ cur_src,
                                              int* __restrict__ cur_dst,
                                              int* __restrict__ srcq,
                                              int* __restrict__ pq,
                                              float* __restrict__ eaq,
                                              float* __restrict__ shq)
{
    const int e = blockIdx.x * 256 + threadIdx.x;   // grid = 1250 exact
    const int s = esrc[e], d = edst[e];
    const int q = atomicAdd(&cur_src[s], 1);
    const int p = atomicAdd(&cur_dst[d], 1);
    srcq[q] = s;
    pq[q] = p;
    float* o = eaq + (size_t)q * 8;
#pragma unroll
    for (int v = 0; v < 7; ++v) o[v] = eag[(size_t)e * 7 + v];
    o[7] = 0.f;
    const float px = pos[3*s+0] - pos[3*d+0];
    const float py = pos[3*s+1] - pos[3*d+1];
    const float pz = pos[3*s+2] - pos[3*d+2];
    const float r2 = px*px + py*py + pz*pz;
    float* sh = shq + (size_t)p * 8;
    sh[0] = 1.7320508f*px;
    sh[1] = 1.7320508f*py;
    sh[2] = 1.7320508f*pz;
    sh[3] = 3.8729833f*px*py;
    sh[4] = 3.8729833f*py*pz;
    sh[5] = 1.1180340f*(3.f*pz*pz - r2);
    sh[6] = 3.8729833f*px*pz;
    sh[7] = 1.9364917f*(px*px - py*py);
}

// ---------------- K4: per-edge h; wave-independent q loop + 1-deep prefetch ----------------

__global__ __launch_bounds__(256) void k_edge_hb(const float* __restrict__ z,
                                                 const int* __restrict__ offs_src,
                                                 const int* __restrict__ srcq,
                                                 const int* __restrict__ pq,
                                                 const float* __restrict__ eaq,
                                                 unsigned short* __restrict__ hbuf)
{
    __shared__ float zl[8 * NZ];   // 23296 B
    const int t = threadIdx.x;
    const int base = blockIdx.x * 8;
    const float4* zg = (const float4*)(z + (size_t)base * NZ);
    float4* zl4 = (float4*)zl;
    for (int i = t; i < (8 * NZ) / 4; i += 256) zl4[i] = zg[i];
    const int qbeg = offs_src[base], qend = offs_src[base + 8];
    __syncthreads();

    const int lane = t & 63, wid = t >> 6;
    int q = qbeg + wid;
    if (q >= qend) return;
    int slot = srcq[q] - base;
    int p = pq[q];
    float4 eA = ((const float4*)(eaq + (size_t)q * 8))[0];
    float4 eB = ((const float4*)(eaq + (size_t)q * 8))[1];

    while (1) {
        const int qn = q + 4;
        const bool more = qn < qend;
        int slotn = 0, pn = 0;
        float4 eAn = eA, eBn = eB;
        if (more) {
            slotn = srcq[qn] - base;
            pn = pq[qn];
            eAn = ((const float4*)(eaq + (size_t)qn * 8))[0];
            eBn = ((const float4*)(eaq + (size_t)qn * 8))[1];
        }
        const float* zr = zl + slot * NZ;
        float h0 = eA.x*zr[lane]       + eA.y*zr[104+lane] + eA.z*zr[208+lane]
                 + eA.w*zr[312+lane]   + eB.x*zr[416+lane] + eB.y*zr[520+lane]
                 + eB.z*zr[624+lane];
        unsigned short* hr = hbuf + (size_t)p * NH;
        hr[lane] = f2bf(h0);
        if (lane < 40) {
            const int c = 64 + lane;
            float h1 = eA.x*zr[c]     + eA.y*zr[104+c] + eA.z*zr[208+c]
                     + eA.w*zr[312+c] + eB.x*zr[416+c] + eB.y*zr[520+c]
                     + eB.z*zr[624+c];
            hr[c] = f2bf(h1);
        }
        if (!more) break;
        slot = slotn; p = pn; eA = eAn; eB = eBn; q = qn;
    }
}

// ---------------- K5: streaming segment-sum by dst (chunk = 8 rows) ----------------

__global__ __launch_bounds__(256) void k_segsum(const unsigned short* __restrict__ hbuf,
                                                const float* __restrict__ shq,
                                                const int* __restrict__ offs_dst,
                                                unsigned short* __restrict__ ncat)
{
    const int node = blockIdx.x;
    const int t = threadIdx.x;
    __shared__ uint4 rows4[8][13];   // 8 rows x 104 bf16
    __shared__ float shl[8][8];

    const int beg = offs_dst[node], end = offs_dst[node + 1];

    int kind, wi = 0, mi = 0;
    if (t < 64) kind = 0;
    else if (t < 136) { const int idx = t - 64;  wi = idx / 3; mi = idx - 3*wi; kind = 1; }
    else if (t < 216) { const int idx = t - 136; wi = idx / 5; mi = idx - 5*wi; kind = 2; }
    else kind = 3;

    float acc = 0.f;
    const uint4* hb4 = (const uint4*)hbuf;   // row p starts at uint4 index p*13 (208B, 16B-aligned)
    for (int j = beg; j < end; j += 8) {
        const int cnt = min(8, end - j);
        __syncthreads();
        if (t < 13 * cnt) {
            const int r = t / 13, c = t - 13 * r;
            rows4[r][c] = hb4[(size_t)(j + r) * 13 + c];
        } else if (t >= 128 && t < 128 + 8 * cnt) {
            const int i = t - 128, r = i / 8, k = i - 8 * r;
            shl[r][k] = shq[(size_t)(j + r) * 8 + k];
        }
        __syncthreads();
        for (int r = 0; r < cnt; ++r) {
            const unsigned short* row = (const unsigned short*)rows4[r];
            if (kind == 0)      acc += bf2f(row[t]);
            else if (kind == 1) acc += bf2f(row[64 + wi]) * shl[r][mi];
            else if (kind == 2) acc += bf2f(row[88 + wi]) * shl[r][3 + mi];
        }
    }
    if (t < NCOMP) ncat[(size_t)node * NCOMP + t] = f2bf(acc);
}

// ---------------- K6: per-edge g -> LDS graph bins -> out (fused phase2+phase3) ----------------

__global__ __launch_bounds__(256) void k_gfinal(const float* __restrict__ pos,
                                                const float* __restrict__ eag,
                                                const int* __restrict__ esrc,
                                                const int* __restrict__ edst,
                                                const int* __restrict__ batch,
                                                const float* __restrict__ V1,
                                                const float* __restrict__ V2,
                                                const float* __restrict__ V3,
                                                const unsigned short* __restrict__ ncat,
                                                float* __restrict__ out)
{
    __shared__ float bins[NG];
    const int t = threadIdx.x;
    bins[t] = 0.f;
    __syncthreads();

    const int e0 = blockIdx.x * 1024;
    for (int it = 0; it < 4; ++it) {
        const int e = e0 + it * 256 + t;
        if (e < NE) {
            const int s = esrc[e], d = edst[e];
            float ea[7];
#pragma unroll
            for (int v = 0; v < 7; ++v) ea[v] = eag[(size_t)e * 7 + v];
            const float px = pos[3*s+0] - pos[3*d+0];
            const float py = pos[3*s+1] - pos[3*d+1];
            const float pz = pos[3*s+2] - pos[3*d+2];
            const float r2 = px*px + py*py + pz*pz;
            const float sh1v[3] = {1.7320508f*px, 1.7320508f*py, 1.7320508f*pz};
            const float sh2v[5] = {3.8729833f*px*py,
                                   3.8729833f*py*pz,
                                   1.1180340f*(3.f*pz*pz - r2),
                                   3.8729833f*px*pz,
                                   1.9364917f*(px*px - py*py)};

            const uint4* nrow = (const uint4*)(ncat + (size_t)s * NCOMP);  // 432B, aligned
            float g0 = 0.f, g1 = 0.f, g2 = 0.f;

#pragma unroll
            for (int c8 = 0; c8 < 8; ++c8) {      // n0: 64 comps
                const uint4 pk = nrow[c8];
                float vals[8];
                unpk2(pk.x, vals[0], vals[1]);
                unpk2(pk.y, vals[2], vals[3]);
                unpk2(pk.z, vals[4], vals[5]);
                unpk2(pk.w, vals[6], vals[7]);
#pragma unroll
                for (int j = 0; j < 8; ++j) {
                    const int u = c8*8 + j;
                    float cu = 0.f;
#pragma unroll
                    for (int v = 0; v < 7; ++v) cu += V1[u*7 + v] * ea[v];
                    g0 += vals[j] * cu;
                }
            }
#pragma unroll
            for (int c8 = 0; c8 < 9; ++c8) {      // n1: 72 comps (u,m) m-fastest
                const uint4 pk = nrow[8 + c8];
                float vals[8];
                unpk2(pk.x, vals[0], vals[1]);
                unpk2(pk.y, vals[2], vals[3]);
                unpk2(pk.z, vals[4], vals[5]);
                unpk2(pk.w, vals[6], vals[7]);
#pragma unroll
                for (int j = 0; j < 8; ++j) {
                    const int i = c8*8 + j;
                    const int u = i / 3, m = i - 3*u;
                    float cu = 0.f;
#pragma unroll
                    for (int v = 0; v < 7; ++v) cu += V2[u*7 + v] * ea[v];
                    g1 += vals[j] * sh1v[m] * cu;
                }
            }
#pragma unroll
            for (int c8 = 0; c8 < 10; ++c8) {     // n2: 80 comps (u,m) m-fastest
                const uint4 pk = nrow[17 + c8];
                float vals[8];
                unpk2(pk.x, vals[0], vals[1]);
                unpk2(pk.y, vals[2], vals[3]);
                unpk2(pk.z, vals[4], vals[5]);
                unpk2(pk.w, vals[6], vals[7]);
#pragma unroll
                for (int j = 0; j < 8; ++j) {
                    const int i = c8*8 + j;
                    const int u = i / 5, m = i - 5*u;
                    float cu = 0.f;
#pragma unroll
                    for (int v = 0; v < 7; ++v) cu += V3[u*7 + v] * ea[v];
                    g2 += vals[j] * sh2v[m] * cu;
                }
            }

            const float g = 0.04724556f*g0 + 0.04454354f*g1 + 0.04225771f*g2;
            atomicAdd(&bins[batch[d]], g);        // LDS atomic (ds_add_f32)
        }
    }
    __syncthreads();
    unsafeAtomicAdd(&out[t], bins[t]);
}

extern "C" void kernel_launch(void* const* d_in, const int* in_sizes, int n_in,
                              void* d_out, int out_size, void* d_ws, size_t ws_size,
                              hipStream_t stream)
{
    const float* pos  = (const float*)d_in[0];
    const float* x    = (const float*)d_in[1];
    const float* eag  = (const float*)d_in[2];
    const int*   eidx = (const int*)d_in[3];
    const int*   batch= (const int*)d_in[4];
    const float* W1   = (const float*)d_in[5];
    const float* W2   = (const float*)d_in[6];
    const float* W3   = (const float*)d_in[7];
    const float* V1   = (const float*)d_in[8];
    const float* V2   = (const float*)d_in[9];
    const float* V3   = (const float*)d_in[10];
    const int* esrc = eidx;
    const int* edst = eidx + NE;

    char* ws = (char*)d_ws;
    size_t off = 0;
    auto alloc = [&](size_t bytes) -> void* {
        void* p = ws + off;
        off = (off + bytes + 255) & ~(size_t)255;
        return p;
    };
    float* z        = (float*)alloc((size_t)NN * NZ * sizeof(float));        // 58.2 MB
    unsigned short* hbuf = (unsigned short*)alloc((size_t)NE * NH * 2);      // 66.6 MB
    float* shq      = (float*)alloc((size_t)NE * 8 * sizeof(float));         // 10.2 MB
    float* eaq      = (float*)alloc((size_t)NE * 8 * sizeof(float));         // 10.2 MB
    unsigned short* ncat = (unsigned short*)alloc((size_t)NN * NCOMP * 2);   // 8.6 MB
    int*   srcq     = (int*)alloc((size_t)NE * sizeof(int));
    int*   pq       = (int*)alloc((size_t)NE * sizeof(int));
    float* Wz       = (float*)alloc((size_t)23 * NZ * sizeof(float));
    int*   deg_src  = (int*)alloc((size_t)NN * sizeof(int));
    int*   deg_dst  = (int*)alloc((size_t)NN * sizeof(int));
    int*   offs_src = (int*)alloc((size_t)(NN + 1) * sizeof(int));
    int*   offs_dst = (int*)alloc((size_t)(NN + 1) * sizeof(int));
    int*   cur_src  = (int*)alloc((size_t)NN * sizeof(int));
    int*   cur_dst  = (int*)alloc((size_t)NN * sizeof(int));

    hipMemsetAsync(deg_src, 0, (size_t)((char*)offs_src - (char*)deg_src), stream);
    hipMemsetAsync(d_out, 0, (size_t)NG * sizeof(float), stream);

    k_count_wz<<<1250 + 66, 256, 0, stream>>>(esrc, edst, W1, W2, W3,
                                              deg_src, deg_dst, Wz);
    k_scan_nodez<<<2 + 313, 256, 0, stream>>>(deg_src, deg_dst, x, Wz,
                                              offs_src, cur_src, offs_dst, cur_dst, z);
    k_fill<<<1250, 256, 0, stream>>>(pos, eag, esrc, edst, cur_src, cur_dst,
                                     srcq, pq, eaq, shq);
    k_edge_hb<<<NN/8, 256, 0, stream>>>(z, offs_src, srcq, pq, eaq, hbuf);
    k_segsum<<<NN, 256, 0, stream>>>(hbuf, shq, offs_dst, ncat);
    k_gfinal<<<(NE + 1023)/1024, 256, 0, stream>>>(pos, eag, esrc, edst, batch,
                                                   V1, V2, V3, ncat, (float*)d_out);
}

// Round 6
// 369.434 us; speedup vs baseline: 10.3616x; 1.0280x over previous
//
#include <hip/hip_runtime.h>

#define NN 20000
#define NE 320000
#define NG 256
#define NZ 728            // 7*104
#define NH 104            // 64+24+16
#define NCOMP 216         // 64 + 24*3 + 16*5

static __device__ __forceinline__ float bf2f(unsigned short u) {
    unsigned int x = ((unsigned int)u) << 16;
    union { unsigned int i; float f; } c; c.i = x; return c.f;
}
static __device__ __forceinline__ unsigned short f2bf(float f) {
    union { float f; unsigned int i; } c; c.f = f;
    unsigned int x = c.i;
    return (unsigned short)((x + 0x7FFFu + ((x >> 16) & 1u)) >> 16);
}
static __device__ __forceinline__ void unpk2(unsigned int w, float& a, float& b) {
    union { unsigned int i; float f; } c0, c1;
    c0.i = w << 16; c1.i = w & 0xFFFF0000u;
    a = c0.f; b = c1.f;
}

// ---------------- K1: blocks [0,1250) count degrees; rest build Wz (24 rows, row23=0) ----------------

__global__ __launch_bounds__(256) void k_count_wz(const int* __restrict__ esrc,
                                                  const int* __restrict__ edst,
                                                  const float* __restrict__ W1,
                                                  const float* __restrict__ W2,
                                                  const float* __restrict__ W3,
                                                  int* __restrict__ deg_src,
                                                  int* __restrict__ deg_dst,
                                                  float* __restrict__ Wz)
{
    const int b = blockIdx.x, t = threadIdx.x;
    if (b < 1250) {
        const int e = b * 256 + t;           // 1250*256 == NE exactly
        atomicAdd(&deg_src[esrc[e]], 1);
        atomicAdd(&deg_dst[edst[e]], 1);
    } else {
        const int idx = (b - 1250) * 256 + t;   // Wz: [u][v*104+w], a1 folded
        if (idx < 24 * NZ) {
            const int u = idx / NZ, c = idx - u * NZ;
            const int v = c / NH, w = c - v * NH;
            float val = 0.f;
            if (u < 23) {
                if (w < 64)      val = W1[(u*7 + v)*64 + w];
                else if (w < 88) val = W2[(u*7 + v)*24 + (w - 64)];
                else             val = W3[(u*7 + v)*16 + (w - 88)];
                val *= 0.07881104f;          // a1 = 1/sqrt(23*7)
            }
            Wz[idx] = val;
        }
    }
}

// ---------------- K2: blocks 0,1 scan src/dst degrees; blocks 2.. node_z (transposed) ----------------
// node_z: 8 nodes/block; thread t owns comps {t, t+256, t+512}; coalesced Wz reads & z writes.

__global__ __launch_bounds__(256) void k_scan_nodez(const int* __restrict__ deg_src,
                                                    const int* __restrict__ deg_dst,
                                                    const float* __restrict__ x,
                                                    const float* __restrict__ Wz,
                                                    int* __restrict__ offs_src,
                                                    int* __restrict__ cur_src,
                                                    int* __restrict__ offs_dst,
                                                    int* __restrict__ cur_dst,
                                                    float* __restrict__ z)
{
    __shared__ __align__(16) char smem[1024];
    const int b = blockIdx.x, t = threadIdx.x;
    if (b < 2) {
        int* part = (int*)smem;
        const int* deg = b ? deg_dst : deg_src;
        int* offs = b ? offs_dst : offs_src;
        int* cur  = b ? cur_dst  : cur_src;
        const int CH = 79;                     // 256*79 >= 20000
        const int base = t * CH;
        int s = 0;
        for (int i = 0; i < CH; ++i) { const int j = base + i; if (j < NN) s += deg[j]; }
        part[t] = s;
        __syncthreads();
        for (int off = 1; off < 256; off <<= 1) {
            int v = 0; if (t >= off) v = part[t - off];
            __syncthreads();
            if (t >= off) part[t] += v;
            __syncthreads();
        }
        int run = t ? part[t - 1] : 0;
        for (int i = 0; i < CH; ++i) {
            const int j = base + i;
            if (j < NN) { offs[j] = run; cur[j] = run; run += deg[j]; }
        }
        if (t == 255) offs[NN] = run;
    } else {
        float (*xa)[24] = (float (*)[24])smem;   // 8 x 24 floats, [*][23]=0 pad
        const int base = (b - 2) * 8;            // grid-2 == 2500, covers NN exactly
        if (t < 192) {
            const int nl = t / 24, u = t - nl * 24;
            xa[nl][u] = (u < 23) ? x[(size_t)(base + nl) * 23 + u] : 0.f;
        }
        __syncthreads();
        const int c0 = t, c1 = t + 256, c2 = t + 512;   // c0,c1 always < 728; c2 iff t<216
        const bool has2 = (c2 < NZ);
        float acc[8][3];
#pragma unroll
        for (int n = 0; n < 8; ++n) { acc[n][0] = 0.f; acc[n][1] = 0.f; acc[n][2] = 0.f; }
#pragma unroll
        for (int u4 = 0; u4 < 24; u4 += 4) {
            float w[4][3];
#pragma unroll
            for (int k = 0; k < 4; ++k) {
                const float* wr = Wz + (u4 + k) * NZ;
                w[k][0] = wr[c0];
                w[k][1] = wr[c1];
                w[k][2] = has2 ? wr[c2] : 0.f;
            }
#pragma unroll
            for (int n = 0; n < 8; ++n) {
                const float4 xv = *(const float4*)&xa[n][u4];   // broadcast ds_read_b128
                acc[n][0] += xv.x*w[0][0] + xv.y*w[1][0] + xv.z*w[2][0] + xv.w*w[3][0];
                acc[n][1] += xv.x*w[0][1] + xv.y*w[1][1] + xv.z*w[2][1] + xv.w*w[3][1];
                acc[n][2] += xv.x*w[0][2] + xv.y*w[1][2] + xv.z*w[2][2] + xv.w*w[3][2];
            }
        }
#pragma unroll
        for (int n = 0; n < 8; ++n) {
            float* zo = z + (size_t)(base + n) * NZ;
            zo[c0] = acc[n][0];
            zo[c1] = acc[n][1];
            if (has2) zo[c2] = acc[n][2];
        }
    }
}

// ---------------- K3: fill dual CSR; pre-gather ea (stride 8) and sh (dst order) ----------------

__global__ __launch_bounds__(256) void k_fill(const float* __restrict__ pos,
                                              const float* __restrict__ eag,
                                              const int* __restrict__ esrc,
                                              const int* __restrict__ edst,
                                              int* __restrict__ cur_src,
                                              int* __restrict__ cur_dst,
                                              int* __restrict__ srcq,
                                              int* __restrict__ pq,
                                              float* __restrict__ eaq,
                                              float* __restrict__ shq)
{
    const int e = blockIdx.x * 256 + threadIdx.x;   // grid = 1250 exact
    const int s = esrc[e], d = edst[e];
    const int q = atomicAdd(&cur_src[s], 1);
    const int p = atomicAdd(&cur_dst[d], 1);
    srcq[q] = s;
    pq[q] = p;
    float* o = eaq + (size_t)q * 8;
#pragma unroll
    for (int v = 0; v < 7; ++v) o[v] = eag[(size_t)e * 7 + v];
    o[7] = 0.f;
    const float px = pos[3*s+0] - pos[3*d+0];
    const float py = pos[3*s+1] - pos[3*d+1];
    const float pz = pos[3*s+2] - pos[3*d+2];
    const float r2 = px*px + py*py + pz*pz;
    float* sh = shq + (size_t)p * 8;
    sh[0] = 1.7320508f*px;
    sh[1] = 1.7320508f*py;
    sh[2] = 1.7320508f*pz;
    sh[3] = 3.8729833f*px*py;
    sh[4] = 3.8729833f*py*pz;
    sh[5] = 1.1180340f*(3.f*pz*pz - r2);
    sh[6] = 3.8729833f*px*pz;
    sh[7] = 1.9364917f*(px*px - py*py);
}

// ---------------- K4: per-edge h; wave-independent q loop + 1-deep prefetch ----------------

__global__ __launch_bounds__(256) void k_edge_hb(const float* __restrict__ z,
                                                 const int* __restrict__ offs_src,
                                                 const int* __restrict__ srcq,
                                                 const int* __restrict__ pq,
                                                 const float* __restrict__ eaq,
                                                 unsigned short* __restrict__ hbuf)
{
    __shared__ float zl[8 * NZ];   // 23296 B
    const int t = threadIdx.x;
    const int base = blockIdx.x * 8;
    const float4* zg = (const float4*)(z + (size_t)base * NZ);
    float4* zl4 = (float4*)zl;
    for (int i = t; i < (8 * NZ) / 4; i += 256) zl4[i] = zg[i];
    const int qbeg = offs_src[base], qend = offs_src[base + 8];
    __syncthreads();

    const int lane = t & 63, wid = t >> 6;
    int q = qbeg + wid;
    if (q >= qend) return;
    int slot = srcq[q] - base;
    int p = pq[q];
    float4 eA = ((const float4*)(eaq + (size_t)q * 8))[0];
    float4 eB = ((const float4*)(eaq + (size_t)q * 8))[1];

    while (1) {
        const int qn = q + 4;
        const bool more = qn < qend;
        int slotn = 0, pn = 0;
        float4 eAn = eA, eBn = eB;
        if (more) {
            slotn = srcq[qn] - base;
            pn = pq[qn];
            eAn = ((const float4*)(eaq + (size_t)qn * 8))[0];
            eBn = ((const float4*)(eaq + (size_t)qn * 8))[1];
        }
        const float* zr = zl + slot * NZ;
        float h0 = eA.x*zr[lane]       + eA.y*zr[104+lane] + eA.z*zr[208+lane]
                 + eA.w*zr[312+lane]   + eB.x*zr[416+lane] + eB.y*zr[520+lane]
                 + eB.z*zr[624+lane];
        unsigned short* hr = hbuf + (size_t)p * NH;
        hr[lane] = f2bf(h0);
        if (lane < 40) {
            const int c = 64 + lane;
            float h1 = eA.x*zr[c]     + eA.y*zr[104+c] + eA.z*zr[208+c]
                     + eA.w*zr[312+c] + eB.x*zr[416+c] + eB.y*zr[520+c]
                     + eB.z*zr[624+c];
            hr[c] = f2bf(h1);
        }
        if (!more) break;
        slot = slotn; p = pn; eA = eAn; eB = eBn; q = qn;
    }
}

// ---------------- K5: streaming segment-sum by dst (chunk = 8 rows) ----------------

__global__ __launch_bounds__(256) void k_segsum(const unsigned short* __restrict__ hbuf,
                                                const float* __restrict__ shq,
                                                const int* __restrict__ offs_dst,
                                                unsigned short* __restrict__ ncat)
{
    const int node = blockIdx.x;
    const int t = threadIdx.x;
    __shared__ uint4 rows4[8][13];   // 8 rows x 104 bf16
    __shared__ float shl[8][8];

    const int beg = offs_dst[node], end = offs_dst[node + 1];

    int kind, wi = 0, mi = 0;
    if (t < 64) kind = 0;
    else if (t < 136) { const int idx = t - 64;  wi = idx / 3; mi = idx - 3*wi; kind = 1; }
    else if (t < 216) { const int idx = t - 136; wi = idx / 5; mi = idx - 5*wi; kind = 2; }
    else kind = 3;

    float acc = 0.f;
    const uint4* hb4 = (const uint4*)hbuf;
    for (int j = beg; j < end; j += 8) {
        const int cnt = min(8, end - j);
        __syncthreads();
        if (t < 13 * cnt) {
            const int r = t / 13, c = t - 13 * r;
            rows4[r][c] = hb4[(size_t)(j + r) * 13 + c];
        } else if (t >= 128 && t < 128 + 8 * cnt) {
            const int i = t - 128, r = i / 8, k = i - 8 * r;
            shl[r][k] = shq[(size_t)(j + r) * 8 + k];
        }
        __syncthreads();
        for (int r = 0; r < cnt; ++r) {
            const unsigned short* row = (const unsigned short*)rows4[r];
            if (kind == 0)      acc += bf2f(row[t]);
            else if (kind == 1) acc += bf2f(row[64 + wi]) * shl[r][mi];
            else if (kind == 2) acc += bf2f(row[88 + wi]) * shl[r][3 + mi];
        }
    }
    if (t < NCOMP) ncat[(size_t)node * NCOMP + t] = f2bf(acc);
}

// ---------------- K6: per-edge g -> LDS graph bins -> out (fused phase2+phase3) ----------------

__global__ __launch_bounds__(256) void k_gfinal(const float* __restrict__ pos,
                                                const float* __restrict__ eag,
                                                const int* __restrict__ esrc,
                                                const int* __restrict__ edst,
                                                const int* __restrict__ batch,
                                                const float* __restrict__ V1,
                                                const float* __restrict__ V2,
                                                const float* __restrict__ V3,
                                                const unsigned short* __restrict__ ncat,
                                                float* __restrict__ out)
{
    __shared__ float bins[NG];
    const int t = threadIdx.x;
    bins[t] = 0.f;
    __syncthreads();

    const int e0 = blockIdx.x * 1024;
    for (int it = 0; it < 4; ++it) {
        const int e = e0 + it * 256 + t;
        if (e < NE) {
            const int s = esrc[e], d = edst[e];
            float ea[7];
#pragma unroll
            for (int v = 0; v < 7; ++v) ea[v] = eag[(size_t)e * 7 + v];
            const float px = pos[3*s+0] - pos[3*d+0];
            const float py = pos[3*s+1] - pos[3*d+1];
            const float pz = pos[3*s+2] - pos[3*d+2];
            const float r2 = px*px + py*py + pz*pz;
            const float sh1v[3] = {1.7320508f*px, 1.7320508f*py, 1.7320508f*pz};
            const float sh2v[5] = {3.8729833f*px*py,
                                   3.8729833f*py*pz,
                                   1.1180340f*(3.f*pz*pz - r2),
                                   3.8729833f*px*pz,
                                   1.9364917f*(px*px - py*py)};

            const uint4* nrow = (const uint4*)(ncat + (size_t)s * NCOMP);  // 432B, aligned
            float g0 = 0.f;
            float gm1[3] = {0.f, 0.f, 0.f};
            float gm2[5] = {0.f, 0.f, 0.f, 0.f, 0.f};

#pragma unroll
            for (int c8 = 0; c8 < 8; ++c8) {      // n0: 64 comps, u = comp
                const uint4 pk = nrow[c8];
                float vals[8];
                unpk2(pk.x, vals[0], vals[1]);
                unpk2(pk.y, vals[2], vals[3]);
                unpk2(pk.z, vals[4], vals[5]);
                unpk2(pk.w, vals[6], vals[7]);
#pragma unroll
                for (int j = 0; j < 8; ++j) {
                    const int u = c8*8 + j;
                    float cu = 0.f;
#pragma unroll
                    for (int v = 0; v < 7; ++v) cu += V1[u*7 + v] * ea[v];
                    g0 += vals[j] * cu;
                }
            }
            {
                float cu = 0.f;                   // n1: 72 comps (u,m) m-fastest
#pragma unroll
                for (int c8 = 0; c8 < 9; ++c8) {
                    const uint4 pk = nrow[8 + c8];
                    float vals[8];
                    unpk2(pk.x, vals[0], vals[1]);
                    unpk2(pk.y, vals[2], vals[3]);
                    unpk2(pk.z, vals[4], vals[5]);
                    unpk2(pk.w, vals[6], vals[7]);
#pragma unroll
                    for (int j = 0; j < 8; ++j) {
                        const int i = c8*8 + j;
                        const int u = i / 3, m = i - 3*u;
                        if (m == 0) {
                            cu = 0.f;
#pragma unroll
                            for (int v = 0; v < 7; ++v) cu += V2[u*7 + v] * ea[v];
                        }
                        gm1[m] += vals[j] * cu;
                    }
                }
            }
            {
                float cu = 0.f;                   // n2: 80 comps (u,m) m-fastest
#pragma unroll
                for (int c8 = 0; c8 < 10; ++c8) {
                    const uint4 pk = nrow[17 + c8];
                    float vals[8];
                    unpk2(pk.x, vals[0], vals[1]);
                    unpk2(pk.y, vals[2], vals[3]);
                    unpk2(pk.z, vals[4], vals[5]);
                    unpk2(pk.w, vals[6], vals[7]);
#pragma unroll
                    for (int j = 0; j < 8; ++j) {
                        const int i = c8*8 + j;
                        const int u = i / 5, m = i - 5*u;
                        if (m == 0) {
                            cu = 0.f;
#pragma unroll
                            for (int v = 0; v < 7; ++v) cu += V3[u*7 + v] * ea[v];
                        }
                        gm2[m] += vals[j] * cu;
                    }
                }
            }

            const float g1 = sh1v[0]*gm1[0] + sh1v[1]*gm1[1] + sh1v[2]*gm1[2];
            const float g2 = sh2v[0]*gm2[0] + sh2v[1]*gm2[1] + sh2v[2]*gm2[2]
                           + sh2v[3]*gm2[3] + sh2v[4]*gm2[4];
            const float g = 0.04724556f*g0 + 0.04454354f*g1 + 0.04225771f*g2;
            atomicAdd(&bins[batch[d]], g);        // LDS atomic (ds_add_f32)
        }
    }
    __syncthreads();
    unsafeAtomicAdd(&out[t], bins[t]);
}

extern "C" void kernel_launch(void* const* d_in, const int* in_sizes, int n_in,
                              void* d_out, int out_size, void* d_ws, size_t ws_size,
                              hipStream_t stream)
{
    const float* pos  = (const float*)d_in[0];
    const float* x    = (const float*)d_in[1];
    const float* eag  = (const float*)d_in[2];
    const int*   eidx = (const int*)d_in[3];
    const int*   batch= (const int*)d_in[4];
    const float* W1   = (const float*)d_in[5];
    const float* W2   = (const float*)d_in[6];
    const float* W3   = (const float*)d_in[7];
    const float* V1   = (const float*)d_in[8];
    const float* V2   = (const float*)d_in[9];
    const float* V3   = (const float*)d_in[10];
    const int* esrc = eidx;
    const int* edst = eidx + NE;

    char* ws = (char*)d_ws;
    size_t off = 0;
    auto alloc = [&](size_t bytes) -> void* {
        void* p = ws + off;
        off = (off + bytes + 255) & ~(size_t)255;
        return p;
    };
    float* z        = (float*)alloc((size_t)NN * NZ * sizeof(float));        // 58.2 MB
    unsigned short* hbuf = (unsigned short*)alloc((size_t)NE * NH * 2);      // 66.6 MB
    float* shq      = (float*)alloc((size_t)NE * 8 * sizeof(float));         // 10.2 MB
    float* eaq      = (float*)alloc((size_t)NE * 8 * sizeof(float));         // 10.2 MB
    unsigned short* ncat = (unsigned short*)alloc((size_t)NN * NCOMP * 2);   // 8.6 MB
    int*   srcq     = (int*)alloc((size_t)NE * sizeof(int));
    int*   pq       = (int*)alloc((size_t)NE * sizeof(int));
    float* Wz       = (float*)alloc((size_t)24 * NZ * sizeof(float));        // 24 rows, row23=0
    int*   deg_src  = (int*)alloc((size_t)NN * sizeof(int));
    int*   deg_dst  = (int*)alloc((size_t)NN * sizeof(int));
    int*   offs_src = (int*)alloc((size_t)(NN + 1) * sizeof(int));
    int*   offs_dst = (int*)alloc((size_t)(NN + 1) * sizeof(int));
    int*   cur_src  = (int*)alloc((size_t)NN * sizeof(int));
    int*   cur_dst  = (int*)alloc((size_t)NN * sizeof(int));

    hipMemsetAsync(deg_src, 0, (size_t)((char*)offs_src - (char*)deg_src), stream);
    hipMemsetAsync(d_out, 0, (size_t)NG * sizeof(float), stream);

    k_count_wz<<<1250 + 69, 256, 0, stream>>>(esrc, edst, W1, W2, W3,
                                              deg_src, deg_dst, Wz);
    k_scan_nodez<<<2 + 2500, 256, 0, stream>>>(deg_src, deg_dst, x, Wz,
                                               offs_src, cur_src, offs_dst, cur_dst, z);
    k_fill<<<1250, 256, 0, stream>>>(pos, eag, esrc, edst, cur_src, cur_dst,
                                     srcq, pq, eaq, shq);
    k_edge_hb<<<NN/8, 256, 0, stream>>>(z, offs_src, srcq, pq, eaq, hbuf);
    k_segsum<<<NN, 256, 0, stream>>>(hbuf, shq, offs_dst, ncat);
    k_gfinal<<<(NE + 1023)/1024, 256, 0, stream>>>(pos, eag, esrc, edst, batch,
                                                   V1, V2, V3, ncat, (float*)d_out);
}

// Round 7
// 343.948 us; speedup vs baseline: 11.1294x; 1.0741x over previous
//
#include <hip/hip_runtime.h>

#define NN 20000
#define NE 320000
#define NG 256
#define NZ 728            // 7*104
#define NH 104            // 64+24+16
#define NCOMP 216         // 64 + 24*3 + 16*5

static __device__ __forceinline__ float bf2f(unsigned short u) {
    unsigned int x = ((unsigned int)u) << 16;
    union { unsigned int i; float f; } c; c.i = x; return c.f;
}
static __device__ __forceinline__ unsigned short f2bf(float f) {
    union { float f; unsigned int i; } c; c.f = f;
    unsigned int x = c.i;
    return (unsigned short)((x + 0x7FFFu + ((x >> 16) & 1u)) >> 16);
}
static __device__ __forceinline__ void unpk2(unsigned int w, float& a, float& b) {
    union { unsigned int i; float f; } c0, c1;
    c0.i = w << 16; c1.i = w & 0xFFFF0000u;
    a = c0.f; b = c1.f;
}

// ---------------- K1: blocks [0,1250) count degrees; rest build Wz (24 rows, row23=0) ----------------

__global__ __launch_bounds__(256) void k_count_wz(const int* __restrict__ esrc,
                                                  const int* __restrict__ edst,
                                                  const float* __restrict__ W1,
                                                  const float* __restrict__ W2,
                                                  const float* __restrict__ W3,
                                                  int* __restrict__ deg_src,
                                                  int* __restrict__ deg_dst,
                                                  float* __restrict__ Wz)
{
    const int b = blockIdx.x, t = threadIdx.x;
    if (b < 1250) {
        const int e = b * 256 + t;           // 1250*256 == NE exactly
        atomicAdd(&deg_src[esrc[e]], 1);
        atomicAdd(&deg_dst[edst[e]], 1);
    } else {
        const int idx = (b - 1250) * 256 + t;   // Wz: [u][v*104+w], a1 folded
        if (idx < 24 * NZ) {
            const int u = idx / NZ, c = idx - u * NZ;
            const int v = c / NH, w = c - v * NH;
            float val = 0.f;
            if (u < 23) {
                if (w < 64)      val = W1[(u*7 + v)*64 + w];
                else if (w < 88) val = W2[(u*7 + v)*24 + (w - 64)];
                else             val = W3[(u*7 + v)*16 + (w - 88)];
                val *= 0.07881104f;          // a1 = 1/sqrt(23*7)
            }
            Wz[idx] = val;
        }
    }
}

// ---------------- K2: blocks 0,1 scan src/dst degrees (shuffle scan, pipelined); ----------------
// ---------------- blocks 2.. node_z (transposed, coalesced)                      ----------------

__global__ __launch_bounds__(256) void k_scan_nodez(const int* __restrict__ deg_src,
                                                    const int* __restrict__ deg_dst,
                                                    const float* __restrict__ x,
                                                    const float* __restrict__ Wz,
                                                    int* __restrict__ offs_src,
                                                    int* __restrict__ cur_src,
                                                    int* __restrict__ offs_dst,
                                                    int* __restrict__ cur_dst,
                                                    float* __restrict__ z)
{
    __shared__ __align__(16) char smem[1024];
    const int b = blockIdx.x, t = threadIdx.x;
    if (b < 2) {
        // chunked coalesced scan: 79 chunks of 256, 1-deep load prefetch
        int* wsum = (int*)smem;                 // [4]
        const int* deg = b ? deg_dst : deg_src;
        int* offs = b ? offs_dst : offs_src;
        int* cur  = b ? cur_dst  : cur_src;
        const int lane = t & 63, wid = t >> 6;
        const int NCH = 79;                     // 79*256 = 20224 >= 20000
        int run = 0;
        int nextv = (t < NN) ? deg[t] : 0;
        for (int c = 0; c < NCH; ++c) {
            const int j = c * 256 + t;
            const int v = nextv;
            const int jn = j + 256;
            nextv = (c + 1 < NCH && jn < NN) ? deg[jn] : 0;   // prefetch next chunk
            // wave-inclusive scan (6 shuffle steps, no barrier)
            int inc = v;
#pragma unroll
            for (int off = 1; off < 64; off <<= 1) {
                const int o = __shfl_up(inc, off, 64);
                if (lane >= off) inc += o;
            }
            if (lane == 63) wsum[wid] = inc;
            __syncthreads();
            int wbase = 0;
#pragma unroll
            for (int wv = 0; wv < 4; ++wv) if (wv < wid) wbase += wsum[wv];
            const int excl = run + wbase + inc - v;
            if (j < NN) { offs[j] = excl; cur[j] = excl; }
            run += wsum[0] + wsum[1] + wsum[2] + wsum[3];     // uniform
            __syncthreads();
        }
        if (t == 255) offs[NN] = run;
    } else {
        float (*xa)[24] = (float (*)[24])smem;   // 8 x 24 floats, [*][23]=0 pad
        const int base = (b - 2) * 8;            // grid-2 == 2500, covers NN exactly
        if (t < 192) {
            const int nl = t / 24, u = t - nl * 24;
            xa[nl][u] = (u < 23) ? x[(size_t)(base + nl) * 23 + u] : 0.f;
        }
        __syncthreads();
        const int c0 = t, c1 = t + 256, c2 = t + 512;   // c0,c1 always < 728; c2 iff t<216
        const bool has2 = (c2 < NZ);
        float acc[8][3];
#pragma unroll
        for (int n = 0; n < 8; ++n) { acc[n][0] = 0.f; acc[n][1] = 0.f; acc[n][2] = 0.f; }
#pragma unroll
        for (int u4 = 0; u4 < 24; u4 += 4) {
            float w[4][3];
#pragma unroll
            for (int k = 0; k < 4; ++k) {
                const float* wr = Wz + (u4 + k) * NZ;
                w[k][0] = wr[c0];
                w[k][1] = wr[c1];
                w[k][2] = has2 ? wr[c2] : 0.f;
            }
#pragma unroll
            for (int n = 0; n < 8; ++n) {
                const float4 xv = *(const float4*)&xa[n][u4];   // broadcast ds_read_b128
                acc[n][0] += xv.x*w[0][0] + xv.y*w[1][0] + xv.z*w[2][0] + xv.w*w[3][0];
                acc[n][1] += xv.x*w[0][1] + xv.y*w[1][1] + xv.z*w[2][1] + xv.w*w[3][1];
                acc[n][2] += xv.x*w[0][2] + xv.y*w[1][2] + xv.z*w[2][2] + xv.w*w[3][2];
            }
        }
#pragma unroll
        for (int n = 0; n < 8; ++n) {
            float* zo = z + (size_t)(base + n) * NZ;
            zo[c0] = acc[n][0];
            zo[c1] = acc[n][1];
            if (has2) zo[c2] = acc[n][2];
        }
    }
}

// ---------------- K3: fill dual CSR; pre-gather ea (stride 8) and sh (dst order) ----------------

__global__ __launch_bounds__(256) void k_fill(const float* __restrict__ pos,
                                              const float* __restrict__ eag,
                                              const int* __restrict__ esrc,
                                              const int* __restrict__ edst,
                                              int* __restrict__ cur_src,
                                              int* __restrict__ cur_dst,
                                              int* __restrict__ srcq,
                                              int* __restrict__ pq,
                                              float* __restrict__ eaq,
                                              float* __restrict__ shq)
{
    const int e = blockIdx.x * 256 + threadIdx.x;   // grid = 1250 exact
    const int s = esrc[e], d = edst[e];
    const int q = atomicAdd(&cur_src[s], 1);
    const int p = atomicAdd(&cur_dst[d], 1);
    srcq[q] = s;
    pq[q] = p;
    float* o = eaq + (size_t)q * 8;
#pragma unroll
    for (int v = 0; v < 7; ++v) o[v] = eag[(size_t)e * 7 + v];
    o[7] = 0.f;
    const float px = pos[3*s+0] - pos[3*d+0];
    const float py = pos[3*s+1] - pos[3*d+1];
    const float pz = pos[3*s+2] - pos[3*d+2];
    const float r2 = px*px + py*py + pz*pz;
    float* sh = shq + (size_t)p * 8;
    sh[0] = 1.7320508f*px;
    sh[1] = 1.7320508f*py;
    sh[2] = 1.7320508f*pz;
    sh[3] = 3.8729833f*px*py;
    sh[4] = 3.8729833f*py*pz;
    sh[5] = 1.1180340f*(3.f*pz*pz - r2);
    sh[6] = 3.8729833f*px*pz;
    sh[7] = 1.9364917f*(px*px - py*py);
}

// ---------------- K4: per-edge h; wave-independent q loop + 1-deep prefetch ----------------

__global__ __launch_bounds__(256) void k_edge_hb(const float* __restrict__ z,
                                                 const int* __restrict__ offs_src,
                                                 const int* __restrict__ srcq,
                                                 const int* __restrict__ pq,
                                                 const float* __restrict__ eaq,
                                                 unsigned short* __restrict__ hbuf)
{
    __shared__ float zl[8 * NZ];   // 23296 B
    const int t = threadIdx.x;
    const int base = blockIdx.x * 8;
    const float4* zg = (const float4*)(z + (size_t)base * NZ);
    float4* zl4 = (float4*)zl;
    for (int i = t; i < (8 * NZ) / 4; i += 256) zl4[i] = zg[i];
    const int qbeg = offs_src[base], qend = offs_src[base + 8];
    __syncthreads();

    const int lane = t & 63, wid = t >> 6;
    int q = qbeg + wid;
    if (q >= qend) return;
    int slot = srcq[q] - base;
    int p = pq[q];
    float4 eA = ((const float4*)(eaq + (size_t)q * 8))[0];
    float4 eB = ((const float4*)(eaq + (size_t)q * 8))[1];

    while (1) {
        const int qn = q + 4;
        const bool more = qn < qend;
        int slotn = 0, pn = 0;
        float4 eAn = eA, eBn = eB;
        if (more) {
            slotn = srcq[qn] - base;
            pn = pq[qn];
            eAn = ((const float4*)(eaq + (size_t)qn * 8))[0];
            eBn = ((const float4*)(eaq + (size_t)qn * 8))[1];
        }
        const float* zr = zl + slot * NZ;
        float h0 = eA.x*zr[lane]       + eA.y*zr[104+lane] + eA.z*zr[208+lane]
                 + eA.w*zr[312+lane]   + eB.x*zr[416+lane] + eB.y*zr[520+lane]
                 + eB.z*zr[624+lane];
        unsigned short* hr = hbuf + (size_t)p * NH;
        hr[lane] = f2bf(h0);
        if (lane < 40) {
            const int c = 64 + lane;
            float h1 = eA.x*zr[c]     + eA.y*zr[104+c] + eA.z*zr[208+c]
                     + eA.w*zr[312+c] + eB.x*zr[416+c] + eB.y*zr[520+c]
                     + eB.z*zr[624+c];
            hr[c] = f2bf(h1);
        }
        if (!more) break;
        slot = slotn; p = pn; eA = eAn; eB = eBn; q = qn;
    }
}

// ---------------- K5: streaming segment-sum by dst (chunk = 8 rows) ----------------

__global__ __launch_bounds__(256) void k_segsum(const unsigned short* __restrict__ hbuf,
                                                const float* __restrict__ shq,
                                                const int* __restrict__ offs_dst,
                                                unsigned short* __restrict__ ncat)
{
    const int node = blockIdx.x;
    const int t = threadIdx.x;
    __shared__ uint4 rows4[8][13];   // 8 rows x 104 bf16
    __shared__ float shl[8][8];

    const int beg = offs_dst[node], end = offs_dst[node + 1];

    int kind, wi = 0, mi = 0;
    if (t < 64) kind = 0;
    else if (t < 136) { const int idx = t - 64;  wi = idx / 3; mi = idx - 3*wi; kind = 1; }
    else if (t < 216) { const int idx = t - 136; wi = idx / 5; mi = idx - 5*wi; kind = 2; }
    else kind = 3;

    float acc = 0.f;
    const uint4* hb4 = (const uint4*)hbuf;
    for (int j = beg; j < end; j += 8) {
        const int cnt = min(8, end - j);
        __syncthreads();
        if (t < 13 * cnt) {
            const int r = t / 13, c = t - 13 * r;
            rows4[r][c] = hb4[(size_t)(j + r) * 13 + c];
        } else if (t >= 128 && t < 128 + 8 * cnt) {
            const int i = t - 128, r = i / 8, k = i - 8 * r;
            shl[r][k] = shq[(size_t)(j + r) * 8 + k];
        }
        __syncthreads();
        for (int r = 0; r < cnt; ++r) {
            const unsigned short* row = (const unsigned short*)rows4[r];
            if (kind == 0)      acc += bf2f(row[t]);
            else if (kind == 1) acc += bf2f(row[64 + wi]) * shl[r][mi];
            else if (kind == 2) acc += bf2f(row[88 + wi]) * shl[r][3 + mi];
        }
    }
    if (t < NCOMP) ncat[(size_t)node * NCOMP + t] = f2bf(acc);
}

// ---------------- K6: per-edge g -> LDS graph bins -> out (fused phase2+phase3) ----------------

__global__ __launch_bounds__(256) void k_gfinal(const float* __restrict__ pos,
                                                const float* __restrict__ eag,
                                                const int* __restrict__ esrc,
                                                const int* __restrict__ edst,
                                                const int* __restrict__ batch,
                                                const float* __restrict__ V1,
                                                const float* __restrict__ V2,
                                                const float* __restrict__ V3,
                                                const unsigned short* __restrict__ ncat,
                                                float* __restrict__ out)
{
    __shared__ float bins[NG];
    const int t = threadIdx.x;
    bins[t] = 0.f;
    __syncthreads();

    const int e0 = blockIdx.x * 1024;
    for (int it = 0; it < 4; ++it) {
        const int e = e0 + it * 256 + t;
        if (e < NE) {
            const int s = esrc[e], d = edst[e];
            float ea[7];
#pragma unroll
            for (int v = 0; v < 7; ++v) ea[v] = eag[(size_t)e * 7 + v];
            const float px = pos[3*s+0] - pos[3*d+0];
            const float py = pos[3*s+1] - pos[3*d+1];
            const float pz = pos[3*s+2] - pos[3*d+2];
            const float r2 = px*px + py*py + pz*pz;
            const float sh1v[3] = {1.7320508f*px, 1.7320508f*py, 1.7320508f*pz};
            const float sh2v[5] = {3.8729833f*px*py,
                                   3.8729833f*py*pz,
                                   1.1180340f*(3.f*pz*pz - r2),
                                   3.8729833f*px*pz,
                                   1.9364917f*(px*px - py*py)};

            const uint4* nrow = (const uint4*)(ncat + (size_t)s * NCOMP);  // 432B, aligned
            float g0 = 0.f;
            float gm1[3] = {0.f, 0.f, 0.f};
            float gm2[5] = {0.f, 0.f, 0.f, 0.f, 0.f};

#pragma unroll
            for (int c8 = 0; c8 < 8; ++c8) {      // n0: 64 comps, u = comp
                const uint4 pk = nrow[c8];
                float vals[8];
                unpk2(pk.x, vals[0], vals[1]);
                unpk2(pk.y, vals[2], vals[3]);
                unpk2(pk.z, vals[4], vals[5]);
                unpk2(pk.w, vals[6], vals[7]);
#pragma unroll
                for (int j = 0; j < 8; ++j) {
                    const int u = c8*8 + j;
                    float cu = 0.f;
#pragma unroll
                    for (int v = 0; v < 7; ++v) cu += V1[u*7 + v] * ea[v];
                    g0 += vals[j] * cu;
                }
            }
            {
                float cu = 0.f;                   // n1: 72 comps (u,m) m-fastest
#pragma unroll
                for (int c8 = 0; c8 < 9; ++c8) {
                    const uint4 pk = nrow[8 + c8];
                    float vals[8];
                    unpk2(pk.x, vals[0], vals[1]);
                    unpk2(pk.y, vals[2], vals[3]);
                    unpk2(pk.z, vals[4], vals[5]);
                    unpk2(pk.w, vals[6], vals[7]);
#pragma unroll
                    for (int j = 0; j < 8; ++j) {
                        const int i = c8*8 + j;
                        const int u = i / 3, m = i - 3*u;
                        if (m == 0) {
                            cu = 0.f;
#pragma unroll
                            for (int v = 0; v < 7; ++v) cu += V2[u*7 + v] * ea[v];
                        }
                        gm1[m] += vals[j] * cu;
                    }
                }
            }
            {
                float cu = 0.f;                   // n2: 80 comps (u,m) m-fastest
#pragma unroll
                for (int c8 = 0; c8 < 10; ++c8) {
                    const uint4 pk = nrow[17 + c8];
                    float vals[8];
                    unpk2(pk.x, vals[0], vals[1]);
                    unpk2(pk.y, vals[2], vals[3]);
                    unpk2(pk.z, vals[4], vals[5]);
                    unpk2(pk.w, vals[6], vals[7]);
#pragma unroll
                    for (int j = 0; j < 8; ++j) {
                        const int i = c8*8 + j;
                        const int u = i / 5, m = i - 5*u;
                        if (m == 0) {
                            cu = 0.f;
#pragma unroll
                            for (int v = 0; v < 7; ++v) cu += V3[u*7 + v] * ea[v];
                        }
                        gm2[m] += vals[j] * cu;
                    }
                }
            }

            const float g1 = sh1v[0]*gm1[0] + sh1v[1]*gm1[1] + sh1v[2]*gm1[2];
            const float g2 = sh2v[0]*gm2[0] + sh2v[1]*gm2[1] + sh2v[2]*gm2[2]
                           + sh2v[3]*gm2[3] + sh2v[4]*gm2[4];
            const float g = 0.04724556f*g0 + 0.04454354f*g1 + 0.04225771f*g2;
            atomicAdd(&bins[batch[d]], g);        // LDS atomic (ds_add_f32)
        }
    }
    __syncthreads();
    unsafeAtomicAdd(&out[t], bins[t]);
}

extern "C" void kernel_launch(void* const* d_in, const int* in_sizes, int n_in,
                              void* d_out, int out_size, void* d_ws, size_t ws_size,
                              hipStream_t stream)
{
    const float* pos  = (const float*)d_in[0];
    const float* x    = (const float*)d_in[1];
    const float* eag  = (const float*)d_in[2];
    const int*   eidx = (const int*)d_in[3];
    const int*   batch= (const int*)d_in[4];
    const float* W1   = (const float*)d_in[5];
    const float* W2   = (const float*)d_in[6];
    const float* W3   = (const float*)d_in[7];
    const float* V1   = (const float*)d_in[8];
    const float* V2   = (const float*)d_in[9];
    const float* V3   = (const float*)d_in[10];
    const int* esrc = eidx;
    const int* edst = eidx + NE;

    char* ws = (char*)d_ws;
    size_t off = 0;
    auto alloc = [&](size_t bytes) -> void* {
        void* p = ws + off;
        off = (off + bytes + 255) & ~(size_t)255;
        return p;
    };
    float* z        = (float*)alloc((size_t)NN * NZ * sizeof(float));        // 58.2 MB
    unsigned short* hbuf = (unsigned short*)alloc((size_t)NE * NH * 2);      // 66.6 MB
    float* shq      = (float*)alloc((size_t)NE * 8 * sizeof(float));         // 10.2 MB
    float* eaq      = (float*)alloc((size_t)NE * 8 * sizeof(float));         // 10.2 MB
    unsigned short* ncat = (unsigned short*)alloc((size_t)NN * NCOMP * 2);   // 8.6 MB
    int*   srcq     = (int*)alloc((size_t)NE * sizeof(int));
    int*   pq       = (int*)alloc((size_t)NE * sizeof(int));
    float* Wz       = (float*)alloc((size_t)24 * NZ * sizeof(float));        // 24 rows, row23=0
    int*   deg_src  = (int*)alloc((size_t)NN * sizeof(int));
    int*   deg_dst  = (int*)alloc((size_t)NN * sizeof(int));
    int*   offs_src = (int*)alloc((size_t)(NN + 1) * sizeof(int));
    int*   offs_dst = (int*)alloc((size_t)(NN + 1) * sizeof(int));
    int*   cur_src  = (int*)alloc((size_t)NN * sizeof(int));
    int*   cur_dst  = (int*)alloc((size_t)NN * sizeof(int));

    hipMemsetAsync(deg_src, 0, (size_t)((char*)offs_src - (char*)deg_src), stream);
    hipMemsetAsync(d_out, 0, (size_t)NG * sizeof(float), stream);

    k_count_wz<<<1250 + 69, 256, 0, stream>>>(esrc, edst, W1, W2, W3,
                                              deg_src, deg_dst, Wz);
    k_scan_nodez<<<2 + 2500, 256, 0, stream>>>(deg_src, deg_dst, x, Wz,
                                               offs_src, cur_src, offs_dst, cur_dst, z);
    k_fill<<<1250, 256, 0, stream>>>(pos, eag, esrc, edst, cur_src, cur_dst,
                                     srcq, pq, eaq, shq);
    k_edge_hb<<<NN/8, 256, 0, stream>>>(z, offs_src, srcq, pq, eaq, hbuf);
    k_segsum<<<NN, 256, 0, stream>>>(hbuf, shq, offs_dst, ncat);
    k_gfinal<<<(NE + 1023)/1024, 256, 0, stream>>>(pos, eag, esrc, edst, batch,
                                                   V1, V2, V3, ncat, (float*)d_out);
}